// Round 1
// baseline (2853.369 us; speedup 1.0000x reference)
//
#include <hip/hip_runtime.h>
#include <math.h>

#define Bb 2
#define Dm 192
#define NHh 8
#define HDd 24
#define N0 9216
#define N1 2304
#define LSEQ 11520
#define FFD 256

// workspace layout (float offsets)
#define WS_OUT 0
#define WS_POS (WS_OUT + Bb*LSEQ*Dm)            // 4,423,680
#define WS_V   (WS_POS + LSEQ*Dm)               // +2,211,840
#define WS_LOC (WS_V + Bb*NHh*LSEQ*HDd)         // +4,423,680
#define WS_AW  (WS_LOC + Bb*LSEQ*64*2)          // +2,949,120
#define WS_ATT (WS_AW + Bb*LSEQ*64)             // +1,474,560
#define WS_WT  (WS_ATT + Bb*LSEQ*Dm)            // +4,423,680
#define WS_GNS (WS_WT + 2*Dm*Dm)                // +73,728
// total = WS_GNS + 256 floats  (~76 MiB)

// -------------------- pos embed --------------------
__global__ void k_pos(float* pos, const float* level_embed) {
    int idx = blockIdx.x * 256 + threadIdx.x;
    if (idx >= LSEQ * Dm) return;
    int t = idx / Dm, d = idx % Dm;
    int lvl, row, col, H, W;
    if (t < N0) { lvl = 0; H = 96; W = 96; row = t / 96; col = t % 96; }
    else        { lvl = 1; H = 48; W = 48; int tl = t - N0; row = tl / 48; col = tl % 48; }
    int k = d % 96;
    float v;
    if (d < 96) v = (row + 0.5f) / ((float)H + 1e-6f) * 6.2831853071795864f;
    else        v = (col + 0.5f) / ((float)W + 1e-6f) * 6.2831853071795864f;
    float expo = (float)(k - (k & 1)) / 96.0f;
    float tm = powf(10000.0f, expo);
    float p = v / tm;
    float pe = (k & 1) ? cosf(p) : sinf(p);
    pos[idx] = pe + level_embed[lvl * Dm + d];
}

// -------------------- transpose proj weights --------------------
__global__ void k_wt(const float* w0, const float* w1, float* wt) {
    int idx = blockIdx.x * 256 + threadIdx.x;
    if (idx >= 2 * Dm * Dm) return;
    int l = idx / (Dm * Dm); int r = idx % (Dm * Dm);
    int c = r / Dm, o = r % Dm;
    const float* w = l ? w1 : w0;
    wt[idx] = w[o * Dm + c];
}

// -------------------- 1x1 conv (proj) --------------------
__global__ __launch_bounds__(192) void k_conv(const float* feat, const float* wt,
        const float* bias, float* srcp, int HW, int tstart) {
    __shared__ __align__(16) float f[Dm][32];
    int b = blockIdx.y;
    int t0 = blockIdx.x * 32;
    int tid = threadIdx.x;
    for (int idx = tid; idx < Dm * 32; idx += 192) {
        int c = idx >> 5, tl = idx & 31;
        f[c][tl] = feat[((size_t)b * Dm + c) * HW + t0 + tl];
    }
    __syncthreads();
    int o = tid;
    float acc[32];
    float bv = bias[o];
    #pragma unroll
    for (int t = 0; t < 32; t++) acc[t] = bv;
    for (int c = 0; c < Dm; c++) {
        float w = wt[c * Dm + o];
        const float4* row = (const float4*)&f[c][0];
        #pragma unroll
        for (int t4 = 0; t4 < 8; t4++) {
            float4 rv = row[t4];
            acc[t4*4+0] += w * rv.x; acc[t4*4+1] += w * rv.y;
            acc[t4*4+2] += w * rv.z; acc[t4*4+3] += w * rv.w;
        }
    }
    for (int t = 0; t < 32; t++)
        srcp[((size_t)b * LSEQ + tstart + t0 + t) * Dm + o] = acc[t];
}

// -------------------- group norm stats --------------------
__global__ __launch_bounds__(256) void k_gnstats(const float* srcp, float* gns) {
    int bid = blockIdx.x;                 // 0..127 = (b, l, g)
    int b = bid >> 6; int l = (bid >> 5) & 1; int g = bid & 31;
    int n = l ? N1 : N0; int start = l ? N0 : 0;
    int tid = threadIdx.x;
    float s1 = 0.f, s2 = 0.f;
    int total = n * 6;
    for (int idx = tid; idx < total; idx += 256) {
        int t = idx / 6; int j = idx - t * 6;
        float x = srcp[((size_t)b * LSEQ + start + t) * Dm + g * 6 + j];
        s1 += x; s2 += x * x;
    }
    for (int m = 1; m < 64; m <<= 1) { s1 += __shfl_xor(s1, m, 64); s2 += __shfl_xor(s2, m, 64); }
    __shared__ float r1[4], r2[4];
    int wv = tid >> 6, lane = tid & 63;
    if (lane == 0) { r1[wv] = s1; r2[wv] = s2; }
    __syncthreads();
    if (tid == 0) {
        float a = r1[0] + r1[1] + r1[2] + r1[3];
        float q = r2[0] + r2[1] + r2[2] + r2[3];
        float mean = a / (float)total;
        float var = q / (float)total - mean * mean;
        gns[bid * 2] = mean;
        gns[bid * 2 + 1] = rsqrtf(var + 1e-5f);
    }
}

// -------------------- group norm apply --------------------
__global__ void k_gnnorm(const float* srcp, const float* gns,
        const float* g0, const float* b0, const float* g1, const float* b1, float* out) {
    int idx = blockIdx.x * 256 + threadIdx.x;
    if (idx >= Bb * LSEQ * Dm) return;
    int d = idx % Dm;
    int t = (idx / Dm) % LSEQ;
    int b = idx / (Dm * LSEQ);
    int l = (t < N0) ? 0 : 1;
    int g = d / 6;
    int sid = ((b * 2 + l) * 32 + g) * 2;
    float mean = gns[sid], rstd = gns[sid + 1];
    float gg = l ? g1[d] : g0[d];
    float bbv = l ? b1[d] : b0[d];
    out[idx] = (srcp[idx] - mean) * rstd * gg + bbv;
}

// -------------------- qkv: offsets, weights(softmax), value proj --------------------
__global__ __launch_bounds__(384) void k_qkv(const float* out, const float* pos,
        const float* soW, const float* soB, const float* awW, const float* awB,
        const float* vpW, const float* vpB,
        float* Vv, float* LOC, float* AW) {
    __shared__ __align__(16) float q_lds[8][Dm];
    __shared__ __align__(16) float o_lds[8][Dm];
    __shared__ float off_lds[8][128];
    __shared__ float aw_lds[8][64];
    int g0 = blockIdx.x * 8;
    int b = g0 / LSEQ;
    int t0 = g0 % LSEQ;
    int tid = threadIdx.x;
    for (int idx = tid; idx < 8 * Dm; idx += 384) {
        int tt = idx / Dm, k = idx % Dm;
        float ov = out[((size_t)b * LSEQ + t0 + tt) * Dm + k];
        o_lds[tt][k] = ov;
        q_lds[tt][k] = ov + pos[(size_t)(t0 + tt) * Dm + k];
    }
    __syncthreads();
    int j = tid;
    const float* Wp; const float* inp; int ldw; int col; float bv;
    if (j < 128)      { Wp = soW; ldw = 128; col = j;       bv = soB[j];       inp = &q_lds[0][0]; }
    else if (j < 192) { Wp = awW; ldw = 64;  col = j - 128; bv = awB[j - 128]; inp = &q_lds[0][0]; }
    else              { Wp = vpW; ldw = Dm;  col = j - 192; bv = vpB[j - 192]; inp = &o_lds[0][0]; }
    float acc[8];
    #pragma unroll
    for (int tt = 0; tt < 8; tt++) acc[tt] = bv;
    for (int k = 0; k < Dm; k += 4) {
        float w0 = Wp[(k+0)*ldw + col], w1 = Wp[(k+1)*ldw + col];
        float w2 = Wp[(k+2)*ldw + col], w3 = Wp[(k+3)*ldw + col];
        #pragma unroll
        for (int tt = 0; tt < 8; tt++) {
            float4 iv = *(const float4*)&inp[tt * Dm + k];
            acc[tt] += iv.x * w0 + iv.y * w1 + iv.z * w2 + iv.w * w3;
        }
    }
    if (j < 128) {
        #pragma unroll
        for (int tt = 0; tt < 8; tt++) off_lds[tt][j] = acc[tt];
    } else if (j < 192) {
        #pragma unroll
        for (int tt = 0; tt < 8; tt++) aw_lds[tt][j - 128] = acc[tt];
    } else {
        int hh = (j - 192) / HDd, dd = (j - 192) % HDd;
        #pragma unroll
        for (int tt = 0; tt < 8; tt++)
            Vv[(((size_t)b * NHh + hh) * LSEQ + t0 + tt) * HDd + dd] = acc[tt];
    }
    __syncthreads();
    if (j < 64) {
        int h = j >> 3, lp = j & 7, l = (lp >> 2);
        float sW = l ? 48.f : 96.f, sH = l ? 48.f : 96.f;
        for (int tt = 0; tt < 8; tt++) {
            int t = t0 + tt;
            float mx = -1e30f;
            #pragma unroll
            for (int q = 0; q < 8; q++) mx = fmaxf(mx, aw_lds[tt][h * 8 + q]);
            float sum = 0.f;
            #pragma unroll
            for (int q = 0; q < 8; q++) sum += expf(aw_lds[tt][h * 8 + q] - mx);
            float myw = expf(aw_lds[tt][j] - mx) / sum;
            AW[(((size_t)b * LSEQ + t) * NHh + h) * 8 + lp] = myw;
            int row, colp, Ht, Wt;
            if (t < N0) { Ht = 96; Wt = 96; row = t / 96; colp = t % 96; }
            else        { Ht = 48; Wt = 48; int tl = t - N0; row = tl / 48; colp = tl % 48; }
            float refx = (colp + 0.5f) / (float)Wt;
            float refy = (row + 0.5f) / (float)Ht;
            float ox = off_lds[tt][2 * j], oy = off_lds[tt][2 * j + 1];
            size_t li = (((size_t)b * LSEQ + t) * 64 + j) * 2;
            LOC[li]     = refx + ox / sW;
            LOC[li + 1] = refy + oy / sH;
        }
    }
}

// -------------------- deformable sampling + head aggregate --------------------
__global__ __launch_bounds__(192) void k_sample(const float* Vv, const float* LOC,
        const float* AW, float* ATT) {
    int tg = blockIdx.x;
    int b = tg / LSEQ, t = tg % LSEQ;
    int h = threadIdx.x / HDd, d = threadIdx.x % HDd;
    const float* vb = Vv + ((size_t)b * NHh + h) * LSEQ * HDd;
    size_t base = (size_t)b * LSEQ + t;
    float acc = 0.f;
    #pragma unroll
    for (int lp = 0; lp < 8; lp++) {
        int l = lp >> 2;
        int Wl = l ? 48 : 96, Hl = l ? 48 : 96, st = l ? N0 : 0;
        float a  = AW[(base * NHh + h) * 8 + lp];
        float lx = LOC[(base * 64 + h * 8 + lp) * 2];
        float ly = LOC[(base * 64 + h * 8 + lp) * 2 + 1];
        float x = lx * (float)Wl - 0.5f, y = ly * (float)Hl - 0.5f;
        float x0 = floorf(x), y0 = floorf(y);
        float wx = x - x0, wy = y - y0;
        float xs[2] = {x0, x0 + 1.f}, ys[2] = {y0, y0 + 1.f};
        float wxs[2] = {1.f - wx, wx}, wys[2] = {1.f - wy, wy};
        float s = 0.f;
        #pragma unroll
        for (int cy = 0; cy < 2; cy++)
        #pragma unroll
        for (int cx = 0; cx < 2; cx++) {
            float xc = xs[cx], yc = ys[cy];
            bool valid = (xc >= 0.f) && (xc <= (float)(Wl - 1)) &&
                         (yc >= 0.f) && (yc <= (float)(Hl - 1));
            int xi = (int)fminf(fmaxf(xc, 0.f), (float)(Wl - 1));
            int yi = (int)fminf(fmaxf(yc, 0.f), (float)(Hl - 1));
            float g = vb[((size_t)(st + yi * Wl + xi)) * HDd + d];
            s += valid ? g * wxs[cx] * wys[cy] : 0.f;
        }
        acc += a * s;
    }
    ATT[base * Dm + threadIdx.x] = acc;
}

// -------------------- output projection + residual (in-place on ATT) --------------------
__global__ __launch_bounds__(192) void k_op(const float* out, const float* W,
        const float* bias, float* att) {
    __shared__ __align__(16) float a_lds[8][Dm];
    int g0 = blockIdx.x * 8; int b = g0 / LSEQ; int t0 = g0 % LSEQ;
    int tid = threadIdx.x;
    for (int idx = tid; idx < 8 * Dm; idx += 192) {
        int tt = idx / Dm, k = idx % Dm;
        a_lds[tt][k] = att[((size_t)b * LSEQ + t0 + tt) * Dm + k];
    }
    __syncthreads();
    int o = tid;
    float acc[8];
    float bv = bias[o];
    #pragma unroll
    for (int tt = 0; tt < 8; tt++) acc[tt] = bv;
    for (int k = 0; k < Dm; k += 4) {
        float w0 = W[(k+0)*Dm + o], w1 = W[(k+1)*Dm + o];
        float w2 = W[(k+2)*Dm + o], w3 = W[(k+3)*Dm + o];
        #pragma unroll
        for (int tt = 0; tt < 8; tt++) {
            float4 iv = *(const float4*)&a_lds[tt][k];
            acc[tt] += iv.x * w0 + iv.y * w1 + iv.z * w2 + iv.w * w3;
        }
    }
    for (int tt = 0; tt < 8; tt++) {
        size_t r = ((size_t)b * LSEQ + t0 + tt) * Dm + o;
        att[r] = acc[tt] + out[r];
    }
}

// -------------------- layer norm (wave per token) --------------------
__global__ __launch_bounds__(256) void k_ln(const float* x, const float* g,
        const float* bt, float* y) {
    int w = threadIdx.x >> 6, lane = threadIdx.x & 63;
    size_t t = (size_t)blockIdx.x * 4 + w;
    const float* row = x + t * Dm;
    float v0 = row[lane], v1 = row[lane + 64], v2 = row[lane + 128];
    float s = v0 + v1 + v2;
    float q = v0 * v0 + v1 * v1 + v2 * v2;
    for (int m = 1; m < 64; m <<= 1) { s += __shfl_xor(s, m, 64); q += __shfl_xor(q, m, 64); }
    float mean = s * (1.f / Dm);
    float var = q * (1.f / Dm) - mean * mean;
    float rstd = rsqrtf(var + 1e-5f);
    float* yr = y + t * Dm;
    yr[lane]       = (v0 - mean) * rstd * g[lane]       + bt[lane];
    yr[lane + 64]  = (v1 - mean) * rstd * g[lane + 64]  + bt[lane + 64];
    yr[lane + 128] = (v2 - mean) * rstd * g[lane + 128] + bt[lane + 128];
}

// -------------------- FFN (192->256 relu ->192) + residual --------------------
__global__ __launch_bounds__(256) void k_ffn(const float* out, const float* w1,
        const float* b1, const float* w2, const float* b2, float* tmp) {
    __shared__ __align__(16) float o_lds[8][Dm];
    __shared__ __align__(16) float h_lds[8][FFD];
    int g0 = blockIdx.x * 8; int b = g0 / LSEQ; int t0 = g0 % LSEQ;
    int tid = threadIdx.x;
    for (int idx = tid; idx < 8 * Dm; idx += 256) {
        int tt = idx / Dm, k = idx % Dm;
        o_lds[tt][k] = out[((size_t)b * LSEQ + t0 + tt) * Dm + k];
    }
    __syncthreads();
    {
        int jc = tid;
        float acc[8];
        float bv = b1[jc];
        #pragma unroll
        for (int tt = 0; tt < 8; tt++) acc[tt] = bv;
        for (int k = 0; k < Dm; k += 4) {
            float wa = w1[(k+0)*FFD + jc], wb = w1[(k+1)*FFD + jc];
            float wc = w1[(k+2)*FFD + jc], wd = w1[(k+3)*FFD + jc];
            #pragma unroll
            for (int tt = 0; tt < 8; tt++) {
                float4 iv = *(const float4*)&o_lds[tt][k];
                acc[tt] += iv.x * wa + iv.y * wb + iv.z * wc + iv.w * wd;
            }
        }
        #pragma unroll
        for (int tt = 0; tt < 8; tt++) h_lds[tt][jc] = fmaxf(acc[tt], 0.f);
    }
    __syncthreads();
    if (tid < Dm) {
        int o = tid;
        float acc2[8];
        float bv = b2[o];
        #pragma unroll
        for (int tt = 0; tt < 8; tt++) acc2[tt] = bv;
        for (int k = 0; k < FFD; k += 4) {
            float wa = w2[(k+0)*Dm + o], wb = w2[(k+1)*Dm + o];
            float wc = w2[(k+2)*Dm + o], wd = w2[(k+3)*Dm + o];
            #pragma unroll
            for (int tt = 0; tt < 8; tt++) {
                float4 iv = *(const float4*)&h_lds[tt][k];
                acc2[tt] += iv.x * wa + iv.y * wb + iv.z * wc + iv.w * wd;
            }
        }
        for (int tt = 0; tt < 8; tt++) {
            size_t r = ((size_t)b * LSEQ + t0 + tt) * Dm + o;
            tmp[r] = acc2[tt] + o_lds[tt][o];
        }
    }
}

// -------------------- final NHWC -> NCHW write --------------------
__global__ void k_out(const float* out, float* dst) {
    int idx = blockIdx.x * 256 + threadIdx.x;
    if (idx >= Bb * Dm * LSEQ) return;
    const int M0 = Bb * Dm * N0;
    size_t src;
    if (idx < M0) {
        int b = idx / (Dm * N0); int r = idx % (Dm * N0);
        int d = r / N0, t = r % N0;
        src = ((size_t)b * LSEQ + t) * Dm + d;
    } else {
        int i2 = idx - M0;
        int b = i2 / (Dm * N1); int r = i2 % (Dm * N1);
        int d = r / N1, t = r % N1;
        src = ((size_t)b * LSEQ + N0 + t) * Dm + d;
    }
    dst[idx] = out[src];
}

extern "C" void kernel_launch(void* const* d_in, const int* in_sizes, int n_in,
                              void* d_out, int out_size, void* d_ws, size_t ws_size,
                              hipStream_t stream) {
    (void)in_sizes; (void)n_in; (void)out_size; (void)ws_size;
    const float* feat0   = (const float*)d_in[0];
    const float* feat1   = (const float*)d_in[1];
    const float* proj_w0 = (const float*)d_in[3];
    const float* proj_b0 = (const float*)d_in[4];
    const float* gn_g0   = (const float*)d_in[5];
    const float* gn_b0   = (const float*)d_in[6];
    const float* proj_w1 = (const float*)d_in[7];
    const float* proj_b1 = (const float*)d_in[8];
    const float* gn_g1   = (const float*)d_in[9];
    const float* gn_b1   = (const float*)d_in[10];
    const float* level_embed = (const float*)d_in[11];
    const float* so_W = (const float*)d_in[12];
    const float* so_b = (const float*)d_in[13];
    const float* aw_W = (const float*)d_in[14];
    const float* aw_b = (const float*)d_in[15];
    const float* vp_W = (const float*)d_in[16];
    const float* vp_b = (const float*)d_in[17];
    const float* op_W = (const float*)d_in[18];
    const float* op_b = (const float*)d_in[19];
    const float* ln1_g = (const float*)d_in[20];
    const float* ln1_b = (const float*)d_in[21];
    const float* l1_W = (const float*)d_in[22];
    const float* l1_b = (const float*)d_in[23];
    const float* l2_W = (const float*)d_in[24];
    const float* l2_b = (const float*)d_in[25];
    const float* ln2_g = (const float*)d_in[26];
    const float* ln2_b = (const float*)d_in[27];

    float* ws  = (float*)d_ws;
    float* OUT = ws + WS_OUT;
    float* POS = ws + WS_POS;
    float* Vv  = ws + WS_V;      // also reused as pre-norm src buffer
    float* LOC = ws + WS_LOC;
    float* AW  = ws + WS_AW;
    float* ATT = ws + WS_ATT;
    float* WT  = ws + WS_WT;
    float* GNS = ws + WS_GNS;

    k_pos<<<(LSEQ * Dm + 255) / 256, 256, 0, stream>>>(POS, level_embed);
    k_wt<<<(2 * Dm * Dm + 255) / 256, 256, 0, stream>>>(proj_w0, proj_w1, WT);
    k_conv<<<dim3(N0 / 32, Bb), 192, 0, stream>>>(feat0, WT, proj_b0, Vv, N0, 0);
    k_conv<<<dim3(N1 / 32, Bb), 192, 0, stream>>>(feat1, WT + Dm * Dm, proj_b1, Vv, N1, N0);
    k_gnstats<<<128, 256, 0, stream>>>(Vv, GNS);
    k_gnnorm<<<(Bb * LSEQ * Dm + 255) / 256, 256, 0, stream>>>(Vv, GNS, gn_g0, gn_b0, gn_g1, gn_b1, OUT);

    for (int i = 0; i < 6; i++) {
        k_qkv<<<Bb * LSEQ / 8, 384, 0, stream>>>(OUT, POS,
            so_W + (size_t)i * Dm * 128, so_b + (size_t)i * 128,
            aw_W + (size_t)i * Dm * 64,  aw_b + (size_t)i * 64,
            vp_W + (size_t)i * Dm * Dm,  vp_b + (size_t)i * Dm,
            Vv, LOC, AW);
        k_sample<<<Bb * LSEQ, 192, 0, stream>>>(Vv, LOC, AW, ATT);
        k_op<<<Bb * LSEQ / 8, 192, 0, stream>>>(OUT, op_W + (size_t)i * Dm * Dm,
            op_b + (size_t)i * Dm, ATT);
        k_ln<<<Bb * LSEQ / 4, 256, 0, stream>>>(ATT, ln1_g + (size_t)i * Dm,
            ln1_b + (size_t)i * Dm, OUT);
        k_ffn<<<Bb * LSEQ / 8, 256, 0, stream>>>(OUT,
            l1_W + (size_t)i * Dm * FFD, l1_b + (size_t)i * FFD,
            l2_W + (size_t)i * FFD * Dm, l2_b + (size_t)i * Dm, ATT);
        k_ln<<<Bb * LSEQ / 4, 256, 0, stream>>>(ATT, ln2_g + (size_t)i * Dm,
            ln2_b + (size_t)i * Dm, OUT);
    }
    k_out<<<(Bb * Dm * LSEQ + 255) / 256, 256, 0, stream>>>(OUT, (float*)d_out);
}

// Round 2
// 1446.329 us; speedup vs baseline: 1.9728x; 1.9728x over previous
//
#include <hip/hip_runtime.h>
#include <hip/hip_bf16.h>
#include <math.h>

#define Bb 2
#define Dm 192
#define NHh 8
#define HDd 24
#define N0 9216
#define N1 2304
#define LSEQ 11520
#define FFD 256
#define Mrows (Bb*LSEQ)            // 23040

typedef __attribute__((ext_vector_type(8))) short short8;
typedef __attribute__((ext_vector_type(4))) float f32x4;

// ---------------- workspace layout (float offsets) ----------------
#define F_OUT 0                         // fp32 [23040][192]
#define F_PRE (F_OUT + 4423680)         // fp32 [23040][192]  (conv-src / RAW / pre-LN)
#define F_POS (F_PRE + 4423680)         // fp32 [11520][192]
#define F_LOC (F_POS + 2211840)         // fp32 [23040][64][2]
#define F_AW  (F_LOC + 2949120)         // fp32 [23040][64]
#define F_QB  (F_AW + 1474560)          // bf16 [23040][192]  (Q;  reused as V)
#define F_OB  (F_QB + 2211840)          // bf16 [23040][192]
#define F_AH  (F_OB + 2211840)          // bf16 [23040][256]  (ATT ∪ hidden)
#define F_WT16 (F_AH + 2949120)         // bf16 weights, 1,253,376 elems
#define F_BC  (F_WT16 + 626688)         // fp32 [6][192] concat so|aw bias
#define F_CWT (F_BC + 1152)             // fp32 conv weights transposed
#define F_GNS (F_CWT + 73728)           // fp32 group-norm stats
// end = F_GNS + 256  -> 23,557,504 floats ~ 94 MB

// per-layer WT16 sub-offsets (bf16 elems)
#define WL_STRIDE 208896
#define WL_SOAW 0
#define WL_VP   36864
#define WL_OP   73728
#define WL_L1   110592
#define WL_L2   159744

__device__ inline __hip_bfloat16 f2b(float f) { return __float2bfloat16(f); }

// -------------------- pos embed --------------------
__global__ void k_pos(float* pos, const float* level_embed) {
    int idx = blockIdx.x * 256 + threadIdx.x;
    if (idx >= LSEQ * Dm) return;
    int t = idx / Dm, d = idx % Dm;
    int lvl, row, col, H, W;
    if (t < N0) { lvl = 0; H = 96; W = 96; row = t / 96; col = t % 96; }
    else        { lvl = 1; H = 48; W = 48; int tl = t - N0; row = tl / 48; col = tl % 48; }
    int k = d % 96;
    float v;
    if (d < 96) v = (row + 0.5f) / ((float)H + 1e-6f) * 6.2831853071795864f;
    else        v = (col + 0.5f) / ((float)W + 1e-6f) * 6.2831853071795864f;
    float expo = (float)(k - (k & 1)) / 96.0f;
    float tm = powf(10000.0f, expo);
    float p = v / tm;
    float pe = (k & 1) ? cosf(p) : sinf(p);
    pos[idx] = pe + level_embed[lvl * Dm + d];
}

// -------------------- transpose conv proj weights (fp32) --------------------
__global__ void k_wt(const float* w0, const float* w1, float* wt) {
    int idx = blockIdx.x * 256 + threadIdx.x;
    if (idx >= 2 * Dm * Dm) return;
    int l = idx / (Dm * Dm); int r = idx % (Dm * Dm);
    int c = r / Dm, o = r % Dm;
    const float* w = l ? w1 : w0;
    wt[idx] = w[o * Dm + c];
}

// -------------------- prep: transpose + bf16-convert all encoder weights ----
__global__ void k_prep(const float* soW, const float* awW, const float* vpW,
        const float* opW, const float* l1W, const float* l2W,
        const float* sob, const float* awb,
        __hip_bfloat16* WT, float* BC) {
    int idx = blockIdx.x * 256 + threadIdx.x;
    if (idx < 6 * 192) {
        int i = idx / 192, n = idx % 192;
        BC[idx] = (n < 128) ? sob[i * 128 + n] : awb[i * 64 + (n - 128)];
    }
    if (idx >= 6 * WL_STRIDE) return;
    int i = idx / WL_STRIDE; int r = idx % WL_STRIDE;
    float v;
    if (r < 36864)       { int n = r / 192, k = r % 192;
        v = (n < 128) ? soW[((size_t)i * 192 + k) * 128 + n]
                      : awW[((size_t)i * 192 + k) * 64 + (n - 128)]; }
    else if (r < 73728)  { int q = r - 36864;  int n = q / 192, k = q % 192;
        v = vpW[((size_t)i * 192 + k) * 192 + n]; }
    else if (r < 110592) { int q = r - 73728;  int n = q / 192, k = q % 192;
        v = opW[((size_t)i * 192 + k) * 192 + n]; }
    else if (r < 159744) { int q = r - 110592; int n = q / 192, k = q % 192;
        v = l1W[((size_t)i * 192 + k) * 256 + n]; }
    else                 { int q = r - 159744; int n = q / 256, k = q % 256;
        v = l2W[((size_t)i * 256 + k) * 192 + n]; }
    WT[idx] = f2b(v);
}

// -------------------- 1x1 conv (proj), fp32 --------------------
__global__ __launch_bounds__(192) void k_conv(const float* feat, const float* wt,
        const float* bias, float* srcp, int HW, int tstart) {
    __shared__ __align__(16) float f[Dm][32];
    int b = blockIdx.y;
    int t0 = blockIdx.x * 32;
    int tid = threadIdx.x;
    for (int idx = tid; idx < Dm * 32; idx += 192) {
        int c = idx >> 5, tl = idx & 31;
        f[c][tl] = feat[((size_t)b * Dm + c) * HW + t0 + tl];
    }
    __syncthreads();
    int o = tid;
    float acc[32];
    float bv = bias[o];
    #pragma unroll
    for (int t = 0; t < 32; t++) acc[t] = bv;
    for (int c = 0; c < Dm; c++) {
        float w = wt[c * Dm + o];
        const float4* row = (const float4*)&f[c][0];
        #pragma unroll
        for (int t4 = 0; t4 < 8; t4++) {
            float4 rv = row[t4];
            acc[t4*4+0] += w * rv.x; acc[t4*4+1] += w * rv.y;
            acc[t4*4+2] += w * rv.z; acc[t4*4+3] += w * rv.w;
        }
    }
    for (int t = 0; t < 32; t++)
        srcp[((size_t)b * LSEQ + tstart + t0 + t) * Dm + o] = acc[t];
}

// -------------------- group norm stats --------------------
__global__ __launch_bounds__(256) void k_gnstats(const float* srcp, float* gns) {
    int bid = blockIdx.x;                 // (b, l, g)
    int b = bid >> 6; int l = (bid >> 5) & 1; int g = bid & 31;
    int n = l ? N1 : N0; int start = l ? N0 : 0;
    int tid = threadIdx.x;
    float s1 = 0.f, s2 = 0.f;
    int total = n * 6;
    for (int idx = tid; idx < total; idx += 256) {
        int t = idx / 6; int j = idx - t * 6;
        float x = srcp[((size_t)b * LSEQ + start + t) * Dm + g * 6 + j];
        s1 += x; s2 += x * x;
    }
    for (int m = 1; m < 64; m <<= 1) { s1 += __shfl_xor(s1, m, 64); s2 += __shfl_xor(s2, m, 64); }
    __shared__ float r1[4], r2[4];
    int wv = tid >> 6, lane = tid & 63;
    if (lane == 0) { r1[wv] = s1; r2[wv] = s2; }
    __syncthreads();
    if (tid == 0) {
        float a = r1[0] + r1[1] + r1[2] + r1[3];
        float q = r2[0] + r2[1] + r2[2] + r2[3];
        float mean = a / (float)total;
        float var = q / (float)total - mean * mean;
        gns[bid * 2] = mean;
        gns[bid * 2 + 1] = rsqrtf(var + 1e-5f);
    }
}

// -------------------- group norm apply: OUT f32 + O bf16 + Q bf16 ----------
__global__ void k_gnnorm(const float* srcp, const float* gns,
        const float* g0, const float* b0, const float* g1, const float* b1,
        const float* pos, float* out, __hip_bfloat16* ob, __hip_bfloat16* qb) {
    int idx = blockIdx.x * 256 + threadIdx.x;
    if (idx >= Bb * LSEQ * Dm) return;
    int d = idx % Dm;
    int t = (idx / Dm) % LSEQ;
    int l = (t < N0) ? 0 : 1;
    int g = d / 6;
    int b = idx / (Dm * LSEQ);
    int sid = ((b * 2 + l) * 32 + g) * 2;
    float mean = gns[sid], rstd = gns[sid + 1];
    float gg = l ? g1[d] : g0[d];
    float bbv = l ? b1[d] : b0[d];
    float v = (srcp[idx] - mean) * rstd * gg + bbv;
    out[idx] = v;
    ob[idx] = f2b(v);
    qb[idx] = f2b(v + pos[idx - (size_t)b * LSEQ * Dm]);
}

// -------------------- bf16 MFMA GEMM: C = A[M,K] * Bt[N,K]^T + bias -------
// grid (M/64, N/64), 256 threads = 4 waves; wave w -> rows [bx*64+w*16, +16)
template<int KSTEPS, bool RELU, bool RESID, bool OUTB>
__global__ __launch_bounds__(256) void k_gemm(
        const __hip_bfloat16* __restrict__ A,
        const __hip_bfloat16* __restrict__ Bt,
        const float* __restrict__ bias,
        const float* __restrict__ resid,
        float* __restrict__ Cf,
        __hip_bfloat16* __restrict__ Cb,
        int N) {
    constexpr int K = KSTEPS * 32;
    int wid = threadIdx.x >> 6, lane = threadIdx.x & 63;
    int lg = lane >> 4, lr = lane & 15;
    int row0 = blockIdx.x * 64 + wid * 16;
    int col0 = blockIdx.y * 64;
    const short* a_base = (const short*)A + (size_t)(row0 + lr) * K + lg * 8;
    const short* b_base = (const short*)Bt + (size_t)(col0 + lr) * K + lg * 8;
    f32x4 acc[4] = {};
    #pragma unroll
    for (int kk = 0; kk < KSTEPS; kk++) {
        short8 af = *(const short8*)(a_base + kk * 32);
        #pragma unroll
        for (int n = 0; n < 4; n++) {
            short8 bfr = *(const short8*)(b_base + (size_t)n * 16 * K + kk * 32);
            acc[n] = __builtin_amdgcn_mfma_f32_16x16x32_bf16(af, bfr, acc[n], 0, 0, 0);
        }
    }
    #pragma unroll
    for (int n = 0; n < 4; n++) {
        int col = col0 + n * 16 + lr;
        float bv = bias[col];
        #pragma unroll
        for (int r = 0; r < 4; r++) {
            int row = row0 + lg * 4 + r;
            float v = acc[n][r] + bv;
            if (RELU) v = fmaxf(v, 0.f);
            size_t o = (size_t)row * N + col;
            if (RESID) v += resid[o];
            if (OUTB) Cb[o] = f2b(v);
            else      Cf[o] = v;
        }
    }
}

// -------------------- loc + softmax(attn weights) from RAW -----------------
__global__ void k_locaw(const float* __restrict__ RAW, float* __restrict__ LOC,
        float* __restrict__ AW) {
    int idx = blockIdx.x * 256 + threadIdx.x;
    if (idx >= Mrows * 64) return;
    int j = idx & 63; int tg = idx >> 6;
    int t = tg % LSEQ;
    int h = j >> 3, lp = j & 7, l = lp >> 2;
    const float* row = RAW + (size_t)tg * 192;
    float mx = -1e30f;
    #pragma unroll
    for (int q = 0; q < 8; q++) mx = fmaxf(mx, row[128 + h * 8 + q]);
    float sum = 0.f;
    #pragma unroll
    for (int q = 0; q < 8; q++) sum += expf(row[128 + h * 8 + q] - mx);
    AW[idx] = expf(row[128 + j] - mx) / sum;
    int rr, cc, Ht, Wt;
    if (t < N0) { Ht = 96; Wt = 96; rr = t / 96; cc = t % 96; }
    else        { Ht = 48; Wt = 48; int tl = t - N0; rr = tl / 48; cc = tl % 48; }
    float refx = (cc + 0.5f) / (float)Wt;
    float refy = (rr + 0.5f) / (float)Ht;
    float sc = l ? 48.f : 96.f;
    LOC[(size_t)idx * 2]     = refx + row[2 * j]     / sc;
    LOC[(size_t)idx * 2 + 1] = refy + row[2 * j + 1] / sc;
}

// -------------------- deformable sampling (bf16 V) -> bf16 ATT -------------
__global__ __launch_bounds__(192) void k_sample(const __hip_bfloat16* __restrict__ V,
        const float* __restrict__ LOC, const float* __restrict__ AW,
        __hip_bfloat16* __restrict__ ATT) {
    int tg = blockIdx.x;
    int b = tg / LSEQ;
    int h = threadIdx.x / HDd, d = threadIdx.x % HDd;
    const __hip_bfloat16* vb = V + (size_t)b * LSEQ * Dm + h * HDd + d;
    float acc = 0.f;
    #pragma unroll
    for (int lp = 0; lp < 8; lp++) {
        int l = lp >> 2;
        int Wl = l ? 48 : 96, Hl = l ? 48 : 96, st = l ? N0 : 0;
        float a  = AW[(size_t)tg * 64 + h * 8 + lp];
        float lx = LOC[((size_t)tg * 64 + h * 8 + lp) * 2];
        float ly = LOC[((size_t)tg * 64 + h * 8 + lp) * 2 + 1];
        float x = lx * (float)Wl - 0.5f, y = ly * (float)Hl - 0.5f;
        float x0 = floorf(x), y0 = floorf(y);
        float wx = x - x0, wy = y - y0;
        float xs[2] = {x0, x0 + 1.f}, ys[2] = {y0, y0 + 1.f};
        float wxs[2] = {1.f - wx, wx}, wys[2] = {1.f - wy, wy};
        float s = 0.f;
        #pragma unroll
        for (int cy = 0; cy < 2; cy++)
        #pragma unroll
        for (int cx = 0; cx < 2; cx++) {
            float xc = xs[cx], yc = ys[cy];
            bool valid = (xc >= 0.f) && (xc <= (float)(Wl - 1)) &&
                         (yc >= 0.f) && (yc <= (float)(Hl - 1));
            int xi = (int)fminf(fmaxf(xc, 0.f), (float)(Wl - 1));
            int yi = (int)fminf(fmaxf(yc, 0.f), (float)(Hl - 1));
            float g = __bfloat162float(vb[(size_t)(st + yi * Wl + xi) * Dm]);
            s += valid ? g * wxs[cx] * wys[cy] : 0.f;
        }
        acc += a * s;
    }
    ATT[(size_t)tg * Dm + threadIdx.x] = f2b(acc);
}

// -------------------- layer norm: y f32 + y bf16 (+ q bf16 w/ pos) ---------
template<bool WQ>
__global__ __launch_bounds__(256) void k_ln(const float* __restrict__ x,
        const float* __restrict__ g, const float* __restrict__ bt,
        const float* __restrict__ pos, float* __restrict__ y,
        __hip_bfloat16* __restrict__ yb, __hip_bfloat16* __restrict__ qb) {
    int w = threadIdx.x >> 6, lane = threadIdx.x & 63;
    size_t t = (size_t)blockIdx.x * 4 + w;
    const float* row = x + t * Dm;
    float v0 = row[lane], v1 = row[lane + 64], v2 = row[lane + 128];
    float s = v0 + v1 + v2;
    float q = v0 * v0 + v1 * v1 + v2 * v2;
    for (int m = 1; m < 64; m <<= 1) { s += __shfl_xor(s, m, 64); q += __shfl_xor(q, m, 64); }
    float mean = s * (1.f / Dm);
    float var = q * (1.f / Dm) - mean * mean;
    float rstd = rsqrtf(var + 1e-5f);
    float o0 = (v0 - mean) * rstd * g[lane]       + bt[lane];
    float o1 = (v1 - mean) * rstd * g[lane + 64]  + bt[lane + 64];
    float o2 = (v2 - mean) * rstd * g[lane + 128] + bt[lane + 128];
    size_t o = t * Dm;
    y[o + lane] = o0; y[o + lane + 64] = o1; y[o + lane + 128] = o2;
    yb[o + lane] = f2b(o0); yb[o + lane + 64] = f2b(o1); yb[o + lane + 128] = f2b(o2);
    if (WQ) {
        size_t tp = (t % LSEQ) * Dm;
        qb[o + lane]       = f2b(o0 + pos[tp + lane]);
        qb[o + lane + 64]  = f2b(o1 + pos[tp + lane + 64]);
        qb[o + lane + 128] = f2b(o2 + pos[tp + lane + 128]);
    }
}

// -------------------- final NHWC -> NCHW write --------------------
__global__ void k_out(const float* out, float* dst) {
    int idx = blockIdx.x * 256 + threadIdx.x;
    if (idx >= Bb * Dm * LSEQ) return;
    const int M0 = Bb * Dm * N0;
    size_t src;
    if (idx < M0) {
        int b = idx / (Dm * N0); int r = idx % (Dm * N0);
        int d = r / N0, t = r % N0;
        src = ((size_t)b * LSEQ + t) * Dm + d;
    } else {
        int i2 = idx - M0;
        int b = i2 / (Dm * N1); int r = i2 % (Dm * N1);
        int d = r / N1, t = r % N1;
        src = ((size_t)b * LSEQ + N0 + t) * Dm + d;
    }
    dst[idx] = out[src];
}

extern "C" void kernel_launch(void* const* d_in, const int* in_sizes, int n_in,
                              void* d_out, int out_size, void* d_ws, size_t ws_size,
                              hipStream_t stream) {
    (void)in_sizes; (void)n_in; (void)out_size; (void)ws_size;
    const float* feat0   = (const float*)d_in[0];
    const float* feat1   = (const float*)d_in[1];
    const float* proj_w0 = (const float*)d_in[3];
    const float* proj_b0 = (const float*)d_in[4];
    const float* gn_g0   = (const float*)d_in[5];
    const float* gn_b0   = (const float*)d_in[6];
    const float* proj_w1 = (const float*)d_in[7];
    const float* proj_b1 = (const float*)d_in[8];
    const float* gn_g1   = (const float*)d_in[9];
    const float* gn_b1   = (const float*)d_in[10];
    const float* level_embed = (const float*)d_in[11];
    const float* so_W = (const float*)d_in[12];
    const float* so_b = (const float*)d_in[13];
    const float* aw_W = (const float*)d_in[14];
    const float* aw_b = (const float*)d_in[15];
    const float* vp_W = (const float*)d_in[16];
    const float* vp_b = (const float*)d_in[17];
    const float* op_W = (const float*)d_in[18];
    const float* op_b = (const float*)d_in[19];
    const float* ln1_g = (const float*)d_in[20];
    const float* ln1_b = (const float*)d_in[21];
    const float* l1_W = (const float*)d_in[22];
    const float* l1_b = (const float*)d_in[23];
    const float* l2_W = (const float*)d_in[24];
    const float* l2_b = (const float*)d_in[25];
    const float* ln2_g = (const float*)d_in[26];
    const float* ln2_b = (const float*)d_in[27];

    float* ws   = (float*)d_ws;
    float* OUT  = ws + F_OUT;
    float* PRE  = ws + F_PRE;
    float* POS  = ws + F_POS;
    float* LOC  = ws + F_LOC;
    float* AWp  = ws + F_AW;
    __hip_bfloat16* QB  = (__hip_bfloat16*)(ws + F_QB);   // also V
    __hip_bfloat16* OB  = (__hip_bfloat16*)(ws + F_OB);
    __hip_bfloat16* AH  = (__hip_bfloat16*)(ws + F_AH);   // ATT / hidden
    __hip_bfloat16* WT16 = (__hip_bfloat16*)(ws + F_WT16);
    float* BC   = ws + F_BC;
    float* CWT  = ws + F_CWT;
    float* GNS  = ws + F_GNS;

    k_pos<<<(LSEQ * Dm + 255) / 256, 256, 0, stream>>>(POS, level_embed);
    k_wt<<<(2 * Dm * Dm + 255) / 256, 256, 0, stream>>>(proj_w0, proj_w1, CWT);
    k_prep<<<(6 * WL_STRIDE + 255) / 256, 256, 0, stream>>>(so_W, aw_W, vp_W, op_W,
        l1_W, l2_W, so_b, aw_b, WT16, BC);
    k_conv<<<dim3(N0 / 32, Bb), 192, 0, stream>>>(feat0, CWT, proj_b0, PRE, N0, 0);
    k_conv<<<dim3(N1 / 32, Bb), 192, 0, stream>>>(feat1, CWT + Dm * Dm, proj_b1, PRE, N1, N0);
    k_gnstats<<<128, 256, 0, stream>>>(PRE, GNS);
    k_gnnorm<<<(Bb * LSEQ * Dm + 255) / 256, 256, 0, stream>>>(PRE, GNS,
        gn_g0, gn_b0, gn_g1, gn_b1, POS, OUT, OB, QB);

    for (int i = 0; i < 6; i++) {
        const __hip_bfloat16* WL = WT16 + (size_t)i * WL_STRIDE;
        // so|aw projection from Q
        k_gemm<6, false, false, false><<<dim3(Mrows / 64, 3), 256, 0, stream>>>(
            QB, WL + WL_SOAW, BC + i * 192, nullptr, PRE, nullptr, 192);
        k_locaw<<<(Mrows * 64 + 255) / 256, 256, 0, stream>>>(PRE, LOC, AWp);
        // value projection from OUT (bf16 out, reuses QB region)
        k_gemm<6, false, false, true><<<dim3(Mrows / 64, 3), 256, 0, stream>>>(
            OB, WL + WL_VP, vp_b + (size_t)i * 192, nullptr, nullptr, QB, 192);
        k_sample<<<Mrows, 192, 0, stream>>>(QB, LOC, AWp, AH);
        // output projection + residual
        k_gemm<6, false, true, false><<<dim3(Mrows / 64, 3), 256, 0, stream>>>(
            AH, WL + WL_OP, op_b + (size_t)i * 192, OUT, PRE, nullptr, 192);
        k_ln<false><<<Mrows / 4, 256, 0, stream>>>(PRE, ln1_g + (size_t)i * 192,
            ln1_b + (size_t)i * 192, nullptr, OUT, OB, nullptr);
        // ffn1 (relu, bf16 out)
        k_gemm<6, true, false, true><<<dim3(Mrows / 64, 4), 256, 0, stream>>>(
            OB, WL + WL_L1, l1_b + (size_t)i * 256, nullptr, nullptr, AH, 256);
        // ffn2 + residual
        k_gemm<8, false, true, false><<<dim3(Mrows / 64, 3), 256, 0, stream>>>(
            AH, WL + WL_L2, l2_b + (size_t)i * 192, OUT, PRE, nullptr, 192);
        k_ln<true><<<Mrows / 4, 256, 0, stream>>>(PRE, ln2_g + (size_t)i * 192,
            ln2_b + (size_t)i * 192, POS, OUT, OB, QB);
    }
    k_out<<<(Bb * Dm * LSEQ + 255) / 256, 256, 0, stream>>>(OUT, (float*)d_out);
}

// Round 3
// 1023.522 us; speedup vs baseline: 2.7878x; 1.4131x over previous
//
#include <hip/hip_runtime.h>
#include <hip/hip_bf16.h>
#include <math.h>

#define Bb 2
#define Dm 192
#define NHh 8
#define HDd 24
#define N0 9216
#define N1 2304
#define LSEQ 11520
#define FFD 256
#define Mrows (Bb*LSEQ)            // 23040

typedef __attribute__((ext_vector_type(8))) short short8;
typedef __attribute__((ext_vector_type(4))) float f32x4;

// ---------------- workspace layout (float offsets) ----------------
#define F_OUT 0                         // fp32 [23040][192]
#define F_PRE (F_OUT + 4423680)         // fp32 [23040][192]  (conv out / GN src)
#define F_POS (F_PRE + 4423680)         // fp32 [11520][192]
#define F_LOC (F_POS + 2211840)         // fp32 [23040][64][2]   (early: FEATB bf16)
#define F_AW  (F_LOC + 2949120)         // fp32 [23040][64]      (early: CWB bf16)
#define F_QB  (F_AW + 1474560)          // bf16 [23040][192]  (Q; reused as V)
#define F_OB  (F_QB + 2211840)          // bf16 [23040][192]
#define F_AH  (F_OB + 2211840)          // bf16 [23040][256]  (ATT/hidden; early: GPART)
#define F_WT16 (F_AH + 2949120)         // bf16 weights, 6*208896 elems
#define F_BC  (F_WT16 + 626688)         // fp32 [6][192] concat so|aw bias
#define F_GNS (F_BC + 1152)             // fp32 group-norm stats (128*2)
// end ~ 23.5M floats ~= 94 MB

// per-layer WT16 sub-offsets (bf16 elems)
#define WL_STRIDE 208896
#define WL_SOAW 0
#define WL_VP   36864
#define WL_OP   73728
#define WL_L1   110592
#define WL_L2   159744

__device__ inline __hip_bfloat16 f2b(float f) { return __float2bfloat16(f); }
__device__ inline unsigned short f2bu(float f) {
    __hip_bfloat16 h = __float2bfloat16(f);
    return *reinterpret_cast<unsigned short*>(&h);
}
__device__ inline float u2f(unsigned short u) {
    unsigned int x = ((unsigned int)u) << 16;
    return __uint_as_float(x);
}

// -------------------- pos embed --------------------
__global__ void k_pos(float* pos, const float* level_embed) {
    int idx = blockIdx.x * 256 + threadIdx.x;
    if (idx >= LSEQ * Dm) return;
    int t = idx / Dm, d = idx % Dm;
    int lvl, row, col, H, W;
    if (t < N0) { lvl = 0; H = 96; W = 96; row = t / 96; col = t % 96; }
    else        { lvl = 1; H = 48; W = 48; int tl = t - N0; row = tl / 48; col = tl % 48; }
    int k = d % 96;
    float v;
    if (d < 96) v = (row + 0.5f) / ((float)H + 1e-6f) * 6.2831853071795864f;
    else        v = (col + 0.5f) / ((float)W + 1e-6f) * 6.2831853071795864f;
    float expo = (float)(k - (k & 1)) / 96.0f;
    float tm = exp2f(expo * 13.287712379549449f);   // 10000^expo
    float p = v / tm;
    float pe = (k & 1) ? cosf(p) : sinf(p);
    pos[idx] = pe + level_embed[lvl * Dm + d];
}

// -------------------- prep: transpose + bf16-convert encoder weights ----
__global__ void k_prep(const float* soW, const float* awW, const float* vpW,
        const float* opW, const float* l1W, const float* l2W,
        const float* sob, const float* awb,
        __hip_bfloat16* WT, float* BC) {
    int idx = blockIdx.x * 256 + threadIdx.x;
    if (idx < 6 * 192) {
        int i = idx / 192, n = idx % 192;
        BC[idx] = (n < 128) ? sob[i * 128 + n] : awb[i * 64 + (n - 128)];
    }
    if (idx >= 6 * WL_STRIDE) return;
    int i = idx / WL_STRIDE; int r = idx % WL_STRIDE;
    float v;
    if (r < 36864)       { int n = r / 192, k = r % 192;
        v = (n < 128) ? soW[((size_t)i * 192 + k) * 128 + n]
                      : awW[((size_t)i * 192 + k) * 64 + (n - 128)]; }
    else if (r < 73728)  { int q = r - 36864;  int n = q / 192, k = q % 192;
        v = vpW[((size_t)i * 192 + k) * 192 + n]; }
    else if (r < 110592) { int q = r - 73728;  int n = q / 192, k = q % 192;
        v = opW[((size_t)i * 192 + k) * 192 + n]; }
    else if (r < 159744) { int q = r - 110592; int n = q / 192, k = q % 192;
        v = l1W[((size_t)i * 192 + k) * 256 + n]; }
    else                 { int q = r - 159744; int n = q / 256, k = q % 256;
        v = l2W[((size_t)i * 256 + k) * 192 + n]; }
    WT[idx] = f2b(v);
}

// conv weights: proj_w is [o][c] which is exactly Bt[N][K] — just convert
__global__ void k_prepc(const float* w0, const float* w1, __hip_bfloat16* cwb) {
    int idx = blockIdx.x * 256 + threadIdx.x;
    if (idx >= 2 * 36864) return;
    const float* w = (idx < 36864) ? w0 : w1;
    int r = idx % 36864;
    cwb[idx] = f2b(w[r]);
}

// -------------------- feature transpose [b][c][t] -> bf16 [t][c] ----------
__global__ void k_tf(const float* feat, __hip_bfloat16* out, int HW, int st) {
    __shared__ float tile[32][33];
    int t0 = blockIdx.x * 32, c0 = blockIdx.y * 32, b = blockIdx.z;
    int tx = threadIdx.x, ty = threadIdx.y;
    #pragma unroll
    for (int k = 0; k < 4; k++) {
        int c = c0 + ty + k * 8;
        tile[ty + k * 8][tx] = feat[((size_t)b * Dm + c) * HW + t0 + tx];
    }
    __syncthreads();
    #pragma unroll
    for (int k = 0; k < 4; k++) {
        int t = t0 + ty + k * 8;
        out[((size_t)b * LSEQ + st + t) * Dm + c0 + tx] = f2b(tile[tx][ty + k * 8]);
    }
}

// -------------------- GN partial sums (coalesced) --------------------
__global__ __launch_bounds__(192) void k_gnp(const float* __restrict__ pre,
        float* __restrict__ part) {
    int bid = blockIdx.x;                 // 0..239
    int b = bid / 120; int r = bid % 120;
    int l = (r >= 96) ? 1 : 0; int ch = l ? (r - 96) : r;
    int start = b * LSEQ + (l ? N0 : 0) + ch * 96;
    int d = threadIdx.x;
    float s = 0.f, sq = 0.f;
    for (int t = 0; t < 96; t++) {
        float x = pre[(size_t)(start + t) * Dm + d];
        s += x; sq += x * x;
    }
    __shared__ float ls[192], lq[192];
    ls[d] = s; lq[d] = sq;
    __syncthreads();
    if (d < 32) {
        float a = 0.f, b2 = 0.f;
        #pragma unroll
        for (int j = 0; j < 6; j++) { a += ls[d * 6 + j]; b2 += lq[d * 6 + j]; }
        part[((size_t)bid * 32 + d) * 2]     = a;
        part[((size_t)bid * 32 + d) * 2 + 1] = b2;
    }
}

__global__ void k_gnf(const float* __restrict__ part, float* __restrict__ gns) {
    int bid = blockIdx.x;                 // (b,l,g): 128
    int b = bid >> 6; int l = (bid >> 5) & 1; int g = bid & 31;
    int nch = l ? 24 : 96;
    int base = b * 120 + (l ? 96 : 0);
    int tid = threadIdx.x;
    float s = 0.f, q = 0.f;
    for (int c = tid; c < nch; c += 64) {
        s += part[((size_t)(base + c) * 32 + g) * 2];
        q += part[((size_t)(base + c) * 32 + g) * 2 + 1];
    }
    for (int m = 1; m < 64; m <<= 1) { s += __shfl_xor(s, m, 64); q += __shfl_xor(q, m, 64); }
    if (tid == 0) {
        float total = (float)((l ? N1 : N0) * 6);
        float mean = s / total;
        float var = q / total - mean * mean;
        gns[bid * 2] = mean;
        gns[bid * 2 + 1] = rsqrtf(var + 1e-5f);
    }
}

// -------------------- group norm apply: OUT f32 + O bf16 + Q bf16 ----------
__global__ void k_gnnorm(const float* srcp, const float* gns,
        const float* g0, const float* b0, const float* g1, const float* b1,
        const float* pos, float* out, __hip_bfloat16* ob, __hip_bfloat16* qb) {
    int idx = blockIdx.x * 256 + threadIdx.x;
    if (idx >= Bb * LSEQ * Dm) return;
    int d = idx % Dm;
    int t = (idx / Dm) % LSEQ;
    int l = (t < N0) ? 0 : 1;
    int g = d / 6;
    int b = idx / (Dm * LSEQ);
    int sid = ((b * 2 + l) * 32 + g) * 2;
    float mean = gns[sid], rstd = gns[sid + 1];
    float gg = l ? g1[d] : g0[d];
    float bbv = l ? b1[d] : b0[d];
    float v = (srcp[idx] - mean) * rstd * gg + bbv;
    out[idx] = v;
    ob[idx] = f2b(v);
    qb[idx] = f2b(v + pos[idx - (size_t)b * LSEQ * Dm]);
}

// -------------------- bf16 MFMA GEMM: C = A[M,K]*Bt[N,K]^T + bias ---------
// grid (M/64, N/64), 256 thr = 4 waves; wave -> 16 rows x 64 cols
template<int KSTEPS, bool RELU, bool RESID, bool OUTB>
__global__ __launch_bounds__(256) void k_gemm(
        const __hip_bfloat16* __restrict__ A,
        const __hip_bfloat16* __restrict__ Bt,
        const float* __restrict__ bias,
        const float* __restrict__ resid,
        float* __restrict__ Cf,
        __hip_bfloat16* __restrict__ Cb,
        int N) {
    constexpr int K = KSTEPS * 32;
    int wid = threadIdx.x >> 6, lane = threadIdx.x & 63;
    int lg = lane >> 4, lr = lane & 15;
    int row0 = blockIdx.x * 64 + wid * 16;
    int col0 = blockIdx.y * 64;
    const short* a_base = (const short*)A + (size_t)(row0 + lr) * K + lg * 8;
    const short* b_base = (const short*)Bt + (size_t)(col0 + lr) * K + lg * 8;
    f32x4 acc[4] = {};
    #pragma unroll
    for (int kk = 0; kk < KSTEPS; kk++) {
        short8 af = *(const short8*)(a_base + kk * 32);
        #pragma unroll
        for (int n = 0; n < 4; n++) {
            short8 bfr = *(const short8*)(b_base + (size_t)n * 16 * K + kk * 32);
            acc[n] = __builtin_amdgcn_mfma_f32_16x16x32_bf16(af, bfr, acc[n], 0, 0, 0);
        }
    }
    #pragma unroll
    for (int n = 0; n < 4; n++) {
        int col = col0 + n * 16 + lr;
        float bv = bias[col];
        #pragma unroll
        for (int r = 0; r < 4; r++) {
            int row = row0 + lg * 4 + r;
            float v = acc[n][r] + bv;
            if (RELU) v = fmaxf(v, 0.f);
            size_t o = (size_t)row * N + col;
            if (RESID) v += resid[o];
            if (OUTB) Cb[o] = f2b(v);
            else      Cf[o] = v;
        }
    }
}

// ------------- fused soaw GEMM + softmax + sampling-loc epilogue ----------
// grid (M/64), 256 thr = 4 waves; wave owns 16 rows x 192 cols
__global__ __launch_bounds__(256) void k_soaw(
        const __hip_bfloat16* __restrict__ A,      // Q bf16 [M][192]
        const __hip_bfloat16* __restrict__ Bt,     // [192][192]
        const float* __restrict__ bias,            // BC row (192)
        float* __restrict__ LOC, float* __restrict__ AW) {
    constexpr int K = 192;
    int wid = threadIdx.x >> 6, lane = threadIdx.x & 63;
    int lg = lane >> 4, lr = lane & 15;
    int row0 = blockIdx.x * 64 + wid * 16;
    const short* a_base = (const short*)A + (size_t)(row0 + lr) * K + lg * 8;
    const short* b_base = (const short*)Bt + (size_t)lr * K + lg * 8;
    f32x4 acc[12] = {};
    #pragma unroll
    for (int kk = 0; kk < 6; kk++) {
        short8 af = *(const short8*)(a_base + kk * 32);
        #pragma unroll
        for (int n = 0; n < 12; n++) {
            short8 bfr = *(const short8*)(b_base + (size_t)n * 16 * K + kk * 32);
            acc[n] = __builtin_amdgcn_mfma_f32_16x16x32_bf16(af, bfr, acc[n], 0, 0, 0);
        }
    }
    #pragma unroll
    for (int n = 0; n < 12; n++) {
        float bv = bias[n * 16 + lr];
        #pragma unroll
        for (int r = 0; r < 4; r++) acc[n][r] += bv;
    }
    // softmax over attn-weight cols (128..191): head = 8 consecutive cols
    #pragma unroll
    for (int n = 8; n < 12; n++) {
        #pragma unroll
        for (int r = 0; r < 4; r++) {
            float v = acc[n][r];
            float m = v;
            m = fmaxf(m, __shfl_xor(m, 1)); m = fmaxf(m, __shfl_xor(m, 2));
            m = fmaxf(m, __shfl_xor(m, 4));
            float e = expf(v - m);
            float sm = e;
            sm += __shfl_xor(sm, 1); sm += __shfl_xor(sm, 2); sm += __shfl_xor(sm, 4);
            int row = row0 + lg * 4 + r;
            AW[(size_t)row * 64 + (n * 16 + lr - 128)] = e / sm;
        }
    }
    // sampling locations from offset cols (0..127)
    #pragma unroll
    for (int r = 0; r < 4; r++) {
        int row = row0 + lg * 4 + r;
        int t = (row >= LSEQ) ? row - LSEQ : row;
        int rr, cc, Ht, Wt;
        if (t < N0) { Ht = 96; Wt = 96; rr = t / 96; cc = t % 96; }
        else        { Ht = 48; Wt = 48; int tl = t - N0; rr = tl / 48; cc = tl % 48; }
        float refx = (cc + 0.5f) / (float)Wt;
        float refy = (rr + 0.5f) / (float)Ht;
        #pragma unroll
        for (int n = 0; n < 8; n++) {
            int col = n * 16 + lr;
            int j = col >> 1, comp = col & 1;
            float sc = (j & 4) ? 48.f : 96.f;
            LOC[(size_t)row * 128 + col] = (comp ? refy : refx) + acc[n][r] / sc;
        }
    }
}

// ------------- fused GEMM + bias + residual + LayerNorm ----------
// grid (M/64), 256 thr; wave owns 16 rows x all 192 cols
template<int KSTEPS, bool WQ>
__global__ __launch_bounds__(256) void k_gemm_ln(
        const __hip_bfloat16* __restrict__ A,
        const __hip_bfloat16* __restrict__ Bt,
        const float* __restrict__ bias,
        const float* __restrict__ resid,
        const float* __restrict__ g, const float* __restrict__ bt,
        const float* __restrict__ pos,
        float* __restrict__ OUTp, __hip_bfloat16* __restrict__ ob,
        __hip_bfloat16* __restrict__ qb) {
    constexpr int K = KSTEPS * 32;
    int wid = threadIdx.x >> 6, lane = threadIdx.x & 63;
    int lg = lane >> 4, lr = lane & 15;
    int row0 = blockIdx.x * 64 + wid * 16;
    const short* a_base = (const short*)A + (size_t)(row0 + lr) * K + lg * 8;
    const short* b_base = (const short*)Bt + (size_t)lr * K + lg * 8;
    f32x4 acc[12] = {};
    #pragma unroll
    for (int kk = 0; kk < KSTEPS; kk++) {
        short8 af = *(const short8*)(a_base + kk * 32);
        #pragma unroll
        for (int n = 0; n < 12; n++) {
            short8 bfr = *(const short8*)(b_base + (size_t)n * 16 * K + kk * 32);
            acc[n] = __builtin_amdgcn_mfma_f32_16x16x32_bf16(af, bfr, acc[n], 0, 0, 0);
        }
    }
    float s[4] = {0.f, 0.f, 0.f, 0.f}, q[4] = {0.f, 0.f, 0.f, 0.f};
    #pragma unroll
    for (int n = 0; n < 12; n++) {
        int col = n * 16 + lr;
        float bv = bias[col];
        #pragma unroll
        for (int r = 0; r < 4; r++) {
            size_t o = (size_t)(row0 + lg * 4 + r) * Dm + col;
            float v = acc[n][r] + bv + resid[o];
            acc[n][r] = v;
            s[r] += v; q[r] += v * v;
        }
    }
    #pragma unroll
    for (int r = 0; r < 4; r++) {
        #pragma unroll
        for (int m = 1; m < 16; m <<= 1) {
            s[r] += __shfl_xor(s[r], m); q[r] += __shfl_xor(q[r], m);
        }
    }
    float mean[4], rstd[4];
    #pragma unroll
    for (int r = 0; r < 4; r++) {
        mean[r] = s[r] * (1.f / Dm);
        float var = q[r] * (1.f / Dm) - mean[r] * mean[r];
        rstd[r] = rsqrtf(var + 1e-5f);
    }
    #pragma unroll
    for (int n = 0; n < 12; n++) {
        int col = n * 16 + lr;
        float gg = g[col], bb = bt[col];
        #pragma unroll
        for (int r = 0; r < 4; r++) {
            int row = row0 + lg * 4 + r;
            size_t o = (size_t)row * Dm + col;
            float y = (acc[n][r] - mean[r]) * rstd[r] * gg + bb;
            OUTp[o] = y;
            ob[o] = f2b(y);
            if (WQ) {
                int tp = (row >= LSEQ) ? row - LSEQ : row;
                qb[o] = f2b(y + pos[(size_t)tp * Dm + col]);
            }
        }
    }
}

// -------------------- deformable sampling (vectorized) -------------
// block = 192 thr = 4 tokens x 48 lanes (8 heads x 6 d-quads)
__global__ __launch_bounds__(192) void k_sample(const __hip_bfloat16* __restrict__ V,
        const float* __restrict__ LOC, const float* __restrict__ AW,
        __hip_bfloat16* __restrict__ ATT) {
    __shared__ float aw_s[4][64];
    __shared__ float loc_s[4][128];
    int tid = threadIdx.x;
    int tg0 = blockIdx.x * 4;
    for (int idx = tid; idx < 256; idx += 192)
        aw_s[idx >> 6][idx & 63] = AW[(size_t)tg0 * 64 + idx];
    for (int idx = tid; idx < 512; idx += 192)
        loc_s[idx >> 7][idx & 127] = LOC[(size_t)tg0 * 128 + idx];
    __syncthreads();
    int tt = tid / 48, lane = tid - tt * 48;
    int h = lane / 6, dq = lane - h * 6;
    int tg = tg0 + tt;
    int b = (tg >= LSEQ) ? 1 : 0;
    const unsigned short* vb = (const unsigned short*)V + (size_t)b * LSEQ * Dm + h * HDd + dq * 4;
    float a0 = 0.f, a1 = 0.f, a2 = 0.f, a3 = 0.f;
    #pragma unroll
    for (int lp = 0; lp < 8; lp++) {
        int l = lp >> 2;
        int Wl = l ? 48 : 96, Hl = l ? 48 : 96, st = l ? N0 : 0;
        float a  = aw_s[tt][h * 8 + lp];
        float lx = loc_s[tt][(h * 8 + lp) * 2];
        float ly = loc_s[tt][(h * 8 + lp) * 2 + 1];
        float x = lx * (float)Wl - 0.5f, y = ly * (float)Hl - 0.5f;
        float x0f = floorf(x), y0f = floorf(y);
        float wx = x - x0f, wy = y - y0f;
        int x0 = (int)x0f, y0 = (int)y0f;
        #pragma unroll
        for (int cy = 0; cy < 2; cy++) {
            int yi = y0 + cy;
            float wyv = cy ? wy : 1.f - wy;
            bool vy = (yi >= 0) && (yi < Hl);
            int yc = min(max(yi, 0), Hl - 1);
            #pragma unroll
            for (int cx = 0; cx < 2; cx++) {
                int xi = x0 + cx;
                float wv = (cx ? wx : 1.f - wx) * wyv;
                bool ok = vy && (xi >= 0) && (xi < Wl);
                int xc = min(max(xi, 0), Wl - 1);
                float cw = ok ? a * wv : 0.f;
                const unsigned short* gp = vb + (size_t)(st + yc * Wl + xc) * Dm;
                ushort4 g4 = *(const ushort4*)gp;
                a0 += cw * u2f(g4.x);
                a1 += cw * u2f(g4.y);
                a2 += cw * u2f(g4.z);
                a3 += cw * u2f(g4.w);
            }
        }
    }
    ushort4 o4;
    o4.x = f2bu(a0); o4.y = f2bu(a1); o4.z = f2bu(a2); o4.w = f2bu(a3);
    *(ushort4*)((unsigned short*)ATT + (size_t)tg * Dm + h * HDd + dq * 4) = o4;
}

// -------------------- final NHWC -> NCHW write --------------------
__global__ void k_out(const float* out, float* dst) {
    int idx = blockIdx.x * 256 + threadIdx.x;
    if (idx >= Bb * Dm * LSEQ) return;
    const int M0 = Bb * Dm * N0;
    size_t src;
    if (idx < M0) {
        int b = idx / (Dm * N0); int r = idx % (Dm * N0);
        int d = r / N0, t = r % N0;
        src = ((size_t)b * LSEQ + t) * Dm + d;
    } else {
        int i2 = idx - M0;
        int b = i2 / (Dm * N1); int r = i2 % (Dm * N1);
        int d = r / N1, t = r % N1;
        src = ((size_t)b * LSEQ + N0 + t) * Dm + d;
    }
    dst[idx] = out[src];
}

extern "C" void kernel_launch(void* const* d_in, const int* in_sizes, int n_in,
                              void* d_out, int out_size, void* d_ws, size_t ws_size,
                              hipStream_t stream) {
    (void)in_sizes; (void)n_in; (void)out_size; (void)ws_size;
    const float* feat0   = (const float*)d_in[0];
    const float* feat1   = (const float*)d_in[1];
    const float* proj_w0 = (const float*)d_in[3];
    const float* proj_b0 = (const float*)d_in[4];
    const float* gn_g0   = (const float*)d_in[5];
    const float* gn_b0   = (const float*)d_in[6];
    const float* proj_w1 = (const float*)d_in[7];
    const float* proj_b1 = (const float*)d_in[8];
    const float* gn_g1   = (const float*)d_in[9];
    const float* gn_b1   = (const float*)d_in[10];
    const float* level_embed = (const float*)d_in[11];
    const float* so_W = (const float*)d_in[12];
    const float* so_b = (const float*)d_in[13];
    const float* aw_W = (const float*)d_in[14];
    const float* aw_b = (const float*)d_in[15];
    const float* vp_W = (const float*)d_in[16];
    const float* vp_b = (const float*)d_in[17];
    const float* op_W = (const float*)d_in[18];
    const float* op_b = (const float*)d_in[19];
    const float* ln1_g = (const float*)d_in[20];
    const float* ln1_b = (const float*)d_in[21];
    const float* l1_W = (const float*)d_in[22];
    const float* l1_b = (const float*)d_in[23];
    const float* l2_W = (const float*)d_in[24];
    const float* l2_b = (const float*)d_in[25];
    const float* ln2_g = (const float*)d_in[26];
    const float* ln2_b = (const float*)d_in[27];

    float* ws   = (float*)d_ws;
    float* OUT  = ws + F_OUT;
    float* PRE  = ws + F_PRE;
    float* POS  = ws + F_POS;
    float* LOC  = ws + F_LOC;
    float* AWp  = ws + F_AW;
    __hip_bfloat16* QB  = (__hip_bfloat16*)(ws + F_QB);   // Q, then V
    __hip_bfloat16* OB  = (__hip_bfloat16*)(ws + F_OB);
    __hip_bfloat16* AH  = (__hip_bfloat16*)(ws + F_AH);   // ATT / hidden
    __hip_bfloat16* WT16 = (__hip_bfloat16*)(ws + F_WT16);
    float* BC   = ws + F_BC;
    float* GNS  = ws + F_GNS;
    // early-phase aliases (consumed before the layer loop)
    __hip_bfloat16* FEATB = (__hip_bfloat16*)(ws + F_LOC);
    __hip_bfloat16* CWB   = (__hip_bfloat16*)(ws + F_AW);
    float* GPART = ws + F_AH;                              // 240*32*2 floats

    k_pos<<<(LSEQ * Dm + 255) / 256, 256, 0, stream>>>(POS, level_embed);
    k_prep<<<(6 * WL_STRIDE + 255) / 256, 256, 0, stream>>>(so_W, aw_W, vp_W, op_W,
        l1_W, l2_W, so_b, aw_b, WT16, BC);
    k_prepc<<<(2 * 36864 + 255) / 256, 256, 0, stream>>>(proj_w0, proj_w1, CWB);
    k_tf<<<dim3(N0 / 32, 6, 2), dim3(32, 8), 0, stream>>>(feat0, FEATB, N0, 0);
    k_tf<<<dim3(N1 / 32, 6, 2), dim3(32, 8), 0, stream>>>(feat1, FEATB, N1, N0);
    // conv as bf16 GEMM, per (b, level)
    for (int b = 0; b < 2; b++) {
        k_gemm<6, false, false, false><<<dim3(N0 / 64, 3), 256, 0, stream>>>(
            FEATB + (size_t)b * LSEQ * Dm, CWB, proj_b0, nullptr,
            PRE + (size_t)b * LSEQ * Dm, nullptr, Dm);
        k_gemm<6, false, false, false><<<dim3(N1 / 64, 3), 256, 0, stream>>>(
            FEATB + ((size_t)b * LSEQ + N0) * Dm, CWB + 36864, proj_b1, nullptr,
            PRE + ((size_t)b * LSEQ + N0) * Dm, nullptr, Dm);
    }
    k_gnp<<<240, 192, 0, stream>>>(PRE, GPART);
    k_gnf<<<128, 64, 0, stream>>>(GPART, GNS);
    k_gnnorm<<<(Bb * LSEQ * Dm + 255) / 256, 256, 0, stream>>>(PRE, GNS,
        gn_g0, gn_b0, gn_g1, gn_b1, POS, OUT, OB, QB);

    for (int i = 0; i < 6; i++) {
        const __hip_bfloat16* WL = WT16 + (size_t)i * WL_STRIDE;
        // so|aw projection + softmax + loc (from Q)
        k_soaw<<<Mrows / 64, 256, 0, stream>>>(QB, WL + WL_SOAW, BC + i * 192, LOC, AWp);
        // value projection from OB (bf16 out into QB region)
        k_gemm<6, false, false, true><<<dim3(Mrows / 64, 3), 256, 0, stream>>>(
            OB, WL + WL_VP, vp_b + (size_t)i * Dm, nullptr, nullptr, QB, Dm);
        k_sample<<<Mrows / 4, 192, 0, stream>>>(QB, LOC, AWp, AH);
        // output projection + residual + LN1
        k_gemm_ln<6, false><<<Mrows / 64, 256, 0, stream>>>(
            AH, WL + WL_OP, op_b + (size_t)i * Dm, OUT,
            ln1_g + (size_t)i * Dm, ln1_b + (size_t)i * Dm, nullptr,
            OUT, OB, nullptr);
        // ffn1 (relu, bf16 out)
        k_gemm<6, true, false, true><<<dim3(Mrows / 64, 4), 256, 0, stream>>>(
            OB, WL + WL_L1, l1_b + (size_t)i * FFD, nullptr, nullptr, AH, FFD);
        // ffn2 + residual + LN2 (+Q for next layer)
        k_gemm_ln<8, true><<<Mrows / 64, 256, 0, stream>>>(
            AH, WL + WL_L2, l2_b + (size_t)i * Dm, OUT,
            ln2_g + (size_t)i * Dm, ln2_b + (size_t)i * Dm, POS,
            OUT, OB, QB);
    }
    k_out<<<(Bb * Dm * LSEQ + 255) / 256, 256, 0, stream>>>(OUT, (float*)d_out);
}

// Round 4
// 876.830 us; speedup vs baseline: 3.2542x; 1.1673x over previous
//
#include <hip/hip_runtime.h>
#include <hip/hip_bf16.h>
#include <math.h>

#define Bb 2
#define Dm 192
#define NHh 8
#define HDd 24
#define N0 9216
#define N1 2304
#define LSEQ 11520
#define FFD 256
#define Mrows (Bb*LSEQ)            // 23040

typedef __attribute__((ext_vector_type(8))) short short8;
typedef __attribute__((ext_vector_type(4))) float f32x4;

// ---------------- workspace layout (float offsets) ----------------
#define F_OUT 0                         // fp32 [23040][192]
#define F_PRE (F_OUT + 4423680)         // fp32 [23040][192]  (conv out / GN src)
#define F_POS (F_PRE + 4423680)         // fp32 [11520][192]
#define F_LOC (F_POS + 2211840)         // fp32 [23040][64][2]   (early: FEATB bf16)
#define F_AW  (F_LOC + 2949120)         // fp32 [23040][64]      (early: CWB bf16)
#define F_QB  (F_AW + 1474560)          // bf16 [23040][192]  (Q)
#define F_OB  (F_QB + 2211840)          // bf16 [23040][192]
#define F_AH  (F_OB + 2211840)          // bf16 [23040][256]  (ATT/hidden; early: GPART)
#define F_WT16 (F_AH + 2949120)         // bf16 weights, 6*208896 elems
#define F_BC  (F_WT16 + 626688)         // fp32 [6][192] concat so|aw bias
#define F_GNS (F_BC + 1152)             // fp32 group-norm stats (128*2)
#define F_VB  (F_GNS + 256)             // bf16 [23040][192]  V (dedicated)
// end ~ 25.7M floats ~= 103 MB (ws = 256 MiB)

// per-layer WT16 sub-offsets (bf16 elems)
#define WL_STRIDE 208896
#define WL_SOAW 0
#define WL_VP   36864
#define WL_OP   73728
#define WL_L1   110592
#define WL_L2   159744

__device__ inline __hip_bfloat16 f2b(float f) { return __float2bfloat16(f); }
__device__ inline unsigned short f2bu(float f) {
    __hip_bfloat16 h = __float2bfloat16(f);
    return *reinterpret_cast<unsigned short*>(&h);
}
__device__ inline float u2f(unsigned short u) {
    unsigned int x = ((unsigned int)u) << 16;
    return __uint_as_float(x);
}

// -------------------- pos embed --------------------
__global__ void k_pos(float* pos, const float* level_embed) {
    int idx = blockIdx.x * 256 + threadIdx.x;
    if (idx >= LSEQ * Dm) return;
    int t = idx / Dm, d = idx % Dm;
    int lvl, row, col, H, W;
    if (t < N0) { lvl = 0; H = 96; W = 96; row = t / 96; col = t % 96; }
    else        { lvl = 1; H = 48; W = 48; int tl = t - N0; row = tl / 48; col = tl % 48; }
    int k = d % 96;
    float v;
    if (d < 96) v = (row + 0.5f) / ((float)H + 1e-6f) * 6.2831853071795864f;
    else        v = (col + 0.5f) / ((float)W + 1e-6f) * 6.2831853071795864f;
    float expo = (float)(k - (k & 1)) / 96.0f;
    float tm = exp2f(expo * 13.287712379549449f);   // 10000^expo
    float p = v / tm;
    float pe = (k & 1) ? cosf(p) : sinf(p);
    pos[idx] = pe + level_embed[lvl * Dm + d];
}

// -------------------- prep: transpose + bf16-convert encoder weights ----
__global__ void k_prep(const float* soW, const float* awW, const float* vpW,
        const float* opW, const float* l1W, const float* l2W,
        const float* sob, const float* awb,
        __hip_bfloat16* WT, float* BC) {
    int idx = blockIdx.x * 256 + threadIdx.x;
    if (idx < 6 * 192) {
        int i = idx / 192, n = idx % 192;
        BC[idx] = (n < 128) ? sob[i * 128 + n] : awb[i * 64 + (n - 128)];
    }
    if (idx >= 6 * WL_STRIDE) return;
    int i = idx / WL_STRIDE; int r = idx % WL_STRIDE;
    float v;
    if (r < 36864)       { int n = r / 192, k = r % 192;
        v = (n < 128) ? soW[((size_t)i * 192 + k) * 128 + n]
                      : awW[((size_t)i * 192 + k) * 64 + (n - 128)]; }
    else if (r < 73728)  { int q = r - 36864;  int n = q / 192, k = q % 192;
        v = vpW[((size_t)i * 192 + k) * 192 + n]; }
    else if (r < 110592) { int q = r - 73728;  int n = q / 192, k = q % 192;
        v = opW[((size_t)i * 192 + k) * 192 + n]; }
    else if (r < 159744) { int q = r - 110592; int n = q / 192, k = q % 192;
        v = l1W[((size_t)i * 192 + k) * 256 + n]; }
    else                 { int q = r - 159744; int n = q / 256, k = q % 256;
        v = l2W[((size_t)i * 256 + k) * 192 + n]; }
    WT[idx] = f2b(v);
}

// conv weights: proj_w is [o][c] which is exactly Bt[N][K] — just convert
__global__ void k_prepc(const float* w0, const float* w1, __hip_bfloat16* cwb) {
    int idx = blockIdx.x * 256 + threadIdx.x;
    if (idx >= 2 * 36864) return;
    const float* w = (idx < 36864) ? w0 : w1;
    int r = idx % 36864;
    cwb[idx] = f2b(w[r]);
}

// -------------------- feature transpose [b][c][t] -> bf16 [t][c] ----------
__global__ void k_tf(const float* feat, __hip_bfloat16* out, int HW, int st) {
    __shared__ float tile[32][33];
    int t0 = blockIdx.x * 32, c0 = blockIdx.y * 32, b = blockIdx.z;
    int tx = threadIdx.x, ty = threadIdx.y;
    #pragma unroll
    for (int k = 0; k < 4; k++) {
        int c = c0 + ty + k * 8;
        tile[ty + k * 8][tx] = feat[((size_t)b * Dm + c) * HW + t0 + tx];
    }
    __syncthreads();
    #pragma unroll
    for (int k = 0; k < 4; k++) {
        int t = t0 + ty + k * 8;
        out[((size_t)b * LSEQ + st + t) * Dm + c0 + tx] = f2b(tile[tx][ty + k * 8]);
    }
}

// -------------------- GN partial sums (coalesced) --------------------
__global__ __launch_bounds__(192) void k_gnp(const float* __restrict__ pre,
        float* __restrict__ part) {
    int bid = blockIdx.x;                 // 0..239
    int b = bid / 120; int r = bid % 120;
    int l = (r >= 96) ? 1 : 0; int ch = l ? (r - 96) : r;
    int start = b * LSEQ + (l ? N0 : 0) + ch * 96;
    int d = threadIdx.x;
    float s = 0.f, sq = 0.f;
    for (int t = 0; t < 96; t++) {
        float x = pre[(size_t)(start + t) * Dm + d];
        s += x; sq += x * x;
    }
    __shared__ float ls[192], lq[192];
    ls[d] = s; lq[d] = sq;
    __syncthreads();
    if (d < 32) {
        float a = 0.f, b2 = 0.f;
        #pragma unroll
        for (int j = 0; j < 6; j++) { a += ls[d * 6 + j]; b2 += lq[d * 6 + j]; }
        part[((size_t)bid * 32 + d) * 2]     = a;
        part[((size_t)bid * 32 + d) * 2 + 1] = b2;
    }
}

__global__ void k_gnf(const float* __restrict__ part, float* __restrict__ gns) {
    int bid = blockIdx.x;                 // (b,l,g): 128
    int b = bid >> 6; int l = (bid >> 5) & 1; int g = bid & 31;
    int nch = l ? 24 : 96;
    int base = b * 120 + (l ? 96 : 0);
    int tid = threadIdx.x;
    float s = 0.f, q = 0.f;
    for (int c = tid; c < nch; c += 64) {
        s += part[((size_t)(base + c) * 32 + g) * 2];
        q += part[((size_t)(base + c) * 32 + g) * 2 + 1];
    }
    for (int m = 1; m < 64; m <<= 1) { s += __shfl_xor(s, m, 64); q += __shfl_xor(q, m, 64); }
    if (tid == 0) {
        float total = (float)((l ? N1 : N0) * 6);
        float mean = s / total;
        float var = q / total - mean * mean;
        gns[bid * 2] = mean;
        gns[bid * 2 + 1] = rsqrtf(var + 1e-5f);
    }
}

// -------------------- group norm apply: OUT f32 + O bf16 + Q bf16 ----------
__global__ void k_gnnorm(const float* srcp, const float* gns,
        const float* g0, const float* b0, const float* g1, const float* b1,
        const float* pos, float* out, __hip_bfloat16* ob, __hip_bfloat16* qb) {
    int idx = blockIdx.x * 256 + threadIdx.x;
    if (idx >= Bb * LSEQ * Dm) return;
    int d = idx % Dm;
    int t = (idx / Dm) % LSEQ;
    int l = (t < N0) ? 0 : 1;
    int g = d / 6;
    int b = idx / (Dm * LSEQ);
    int sid = ((b * 2 + l) * 32 + g) * 2;
    float mean = gns[sid], rstd = gns[sid + 1];
    float gg = l ? g1[d] : g0[d];
    float bbv = l ? b1[d] : b0[d];
    float v = (srcp[idx] - mean) * rstd * gg + bbv;
    out[idx] = v;
    ob[idx] = f2b(v);
    qb[idx] = f2b(v + pos[idx - (size_t)b * LSEQ * Dm]);
}

// -------------------- bf16 MFMA GEMM: C = A[M,K]*Bt[N,K]^T + bias ---------
// grid (M/64, N/64), 256 thr = 4 waves; wave -> 16 rows x 64 cols
template<int KSTEPS, bool RELU, bool RESID, bool OUTB>
__global__ __launch_bounds__(256) void k_gemm(
        const __hip_bfloat16* __restrict__ A,
        const __hip_bfloat16* __restrict__ Bt,
        const float* __restrict__ bias,
        const float* __restrict__ resid,
        float* __restrict__ Cf,
        __hip_bfloat16* __restrict__ Cb,
        int N) {
    constexpr int K = KSTEPS * 32;
    int wid = threadIdx.x >> 6, lane = threadIdx.x & 63;
    int lg = lane >> 4, lr = lane & 15;
    int row0 = blockIdx.x * 64 + wid * 16;
    int col0 = blockIdx.y * 64;
    const short* a_base = (const short*)A + (size_t)(row0 + lr) * K + lg * 8;
    const short* b_base = (const short*)Bt + (size_t)(col0 + lr) * K + lg * 8;
    f32x4 acc[4] = {};
    #pragma unroll
    for (int kk = 0; kk < KSTEPS; kk++) {
        short8 af = *(const short8*)(a_base + kk * 32);
        #pragma unroll
        for (int n = 0; n < 4; n++) {
            short8 bfr = *(const short8*)(b_base + (size_t)n * 16 * K + kk * 32);
            acc[n] = __builtin_amdgcn_mfma_f32_16x16x32_bf16(af, bfr, acc[n], 0, 0, 0);
        }
    }
    #pragma unroll
    for (int n = 0; n < 4; n++) {
        int col = col0 + n * 16 + lr;
        float bv = bias[col];
        #pragma unroll
        for (int r = 0; r < 4; r++) {
            int row = row0 + lg * 4 + r;
            float v = acc[n][r] + bv;
            if (RELU) v = fmaxf(v, 0.f);
            size_t o = (size_t)row * N + col;
            if (RESID) v += resid[o];
            if (OUTB) Cb[o] = f2b(v);
            else      Cf[o] = v;
        }
    }
}

// ------------- merged soaw + value-proj dispatch --------------------------
// grid (Mrows/16, 2); 192 thr = 3 waves, wave w -> cols w*64..w*64+63
// role y==0: soaw from QB (softmax+loc epilogue); y==1: vp from OB -> VB bf16
__global__ __launch_bounds__(192) void k_soawvp(
        const __hip_bfloat16* __restrict__ QB,
        const __hip_bfloat16* __restrict__ OB,
        const __hip_bfloat16* __restrict__ BtS,
        const __hip_bfloat16* __restrict__ BtV,
        const float* __restrict__ biasS,
        const float* __restrict__ biasV,
        float* __restrict__ LOC, float* __restrict__ AW,
        __hip_bfloat16* __restrict__ VB) {
    constexpr int K = 192;
    int wid = threadIdx.x >> 6, lane = threadIdx.x & 63;
    int lg = lane >> 4, lr = lane & 15;
    int row0 = blockIdx.x * 16;
    int col0 = wid * 64;
    int role = blockIdx.y;
    const short* A  = (const short*)(role ? OB : QB);
    const short* Bt = (const short*)(role ? BtV : BtS);
    const float* bias = role ? biasV : biasS;
    const short* a_base = A + (size_t)(row0 + lr) * K + lg * 8;
    const short* b_base = Bt + (size_t)(col0 + lr) * K + lg * 8;
    f32x4 acc[4] = {};
    #pragma unroll
    for (int kk = 0; kk < 6; kk++) {
        short8 af = *(const short8*)(a_base + kk * 32);
        #pragma unroll
        for (int n = 0; n < 4; n++) {
            short8 bfr = *(const short8*)(b_base + (size_t)n * 16 * K + kk * 32);
            acc[n] = __builtin_amdgcn_mfma_f32_16x16x32_bf16(af, bfr, acc[n], 0, 0, 0);
        }
    }
    #pragma unroll
    for (int n = 0; n < 4; n++) {
        float bv = bias[col0 + n * 16 + lr];
        #pragma unroll
        for (int r = 0; r < 4; r++) acc[n][r] += bv;
    }
    if (role) {
        #pragma unroll
        for (int n = 0; n < 4; n++) {
            int col = col0 + n * 16 + lr;
            #pragma unroll
            for (int r = 0; r < 4; r++) {
                int row = row0 + lg * 4 + r;
                VB[(size_t)row * Dm + col] = f2b(acc[n][r]);
            }
        }
    } else if (wid == 2) {
        // attn-weight softmax: head = 8 consecutive cols within this wave
        #pragma unroll
        for (int n = 0; n < 4; n++) {
            #pragma unroll
            for (int r = 0; r < 4; r++) {
                float v = acc[n][r];
                float m = v;
                m = fmaxf(m, __shfl_xor(m, 1)); m = fmaxf(m, __shfl_xor(m, 2));
                m = fmaxf(m, __shfl_xor(m, 4));
                float e = expf(v - m);
                float sm = e;
                sm += __shfl_xor(sm, 1); sm += __shfl_xor(sm, 2); sm += __shfl_xor(sm, 4);
                int row = row0 + lg * 4 + r;
                AW[(size_t)row * 64 + n * 16 + lr] = e / sm;
            }
        }
    } else {
        // sampling locations (cols 0..127)
        #pragma unroll
        for (int r = 0; r < 4; r++) {
            int row = row0 + lg * 4 + r;
            int t = (row >= LSEQ) ? row - LSEQ : row;
            int rr, cc, Ht, Wt;
            if (t < N0) { Ht = 96; Wt = 96; rr = t / 96; cc = t % 96; }
            else        { Ht = 48; Wt = 48; int tl = t - N0; rr = tl / 48; cc = tl % 48; }
            float refx = (cc + 0.5f) / (float)Wt;
            float refy = (rr + 0.5f) / (float)Ht;
            #pragma unroll
            for (int n = 0; n < 4; n++) {
                int col = col0 + n * 16 + lr;
                int j = col >> 1, comp = col & 1;
                float sc = (j & 4) ? 48.f : 96.f;
                LOC[(size_t)row * 128 + col] = (comp ? refy : refx) + acc[n][r] / sc;
            }
        }
    }
}

// ------------- fused GEMM + bias + residual + LayerNorm -------------------
// grid (Mrows/16); 192 thr = 3 waves, wave w -> cols w*64; LDS cross-wave LN
template<int KSTEPS, bool WQ>
__global__ __launch_bounds__(192) void k_gemm_ln(
        const __hip_bfloat16* __restrict__ A,
        const __hip_bfloat16* __restrict__ Bt,
        const float* __restrict__ bias,
        const float* __restrict__ resid,
        const float* __restrict__ g, const float* __restrict__ bt,
        const float* __restrict__ pos,
        float* __restrict__ OUTp, __hip_bfloat16* __restrict__ ob,
        __hip_bfloat16* __restrict__ qb) {
    constexpr int K = KSTEPS * 32;
    int wid = threadIdx.x >> 6, lane = threadIdx.x & 63;
    int lg = lane >> 4, lr = lane & 15;
    int row0 = blockIdx.x * 16;
    int col0 = wid * 64;
    const short* a_base = (const short*)A + (size_t)(row0 + lr) * K + lg * 8;
    const short* b_base = (const short*)Bt + (size_t)(col0 + lr) * K + lg * 8;
    f32x4 acc[4] = {};
    #pragma unroll
    for (int kk = 0; kk < KSTEPS; kk++) {
        short8 af = *(const short8*)(a_base + kk * 32);
        #pragma unroll
        for (int n = 0; n < 4; n++) {
            short8 bfr = *(const short8*)(b_base + (size_t)n * 16 * K + kk * 32);
            acc[n] = __builtin_amdgcn_mfma_f32_16x16x32_bf16(af, bfr, acc[n], 0, 0, 0);
        }
    }
    float s[4] = {0.f, 0.f, 0.f, 0.f}, q[4] = {0.f, 0.f, 0.f, 0.f};
    #pragma unroll
    for (int n = 0; n < 4; n++) {
        int col = col0 + n * 16 + lr;
        float bv = bias[col];
        #pragma unroll
        for (int r = 0; r < 4; r++) {
            size_t o = (size_t)(row0 + lg * 4 + r) * Dm + col;
            float v = acc[n][r] + bv + resid[o];
            acc[n][r] = v;
            s[r] += v; q[r] += v * v;
        }
    }
    #pragma unroll
    for (int r = 0; r < 4; r++) {
        #pragma unroll
        for (int m = 1; m < 16; m <<= 1) {
            s[r] += __shfl_xor(s[r], m); q[r] += __shfl_xor(q[r], m);
        }
    }
    __shared__ float ps[3][16], pq[3][16];
    if (lr == 0) {
        #pragma unroll
        for (int r = 0; r < 4; r++) {
            ps[wid][lg * 4 + r] = s[r];
            pq[wid][lg * 4 + r] = q[r];
        }
    }
    __syncthreads();
    float mean[4], rstd[4];
    #pragma unroll
    for (int r = 0; r < 4; r++) {
        int r16 = lg * 4 + r;
        float S = ps[0][r16] + ps[1][r16] + ps[2][r16];
        float Q = pq[0][r16] + pq[1][r16] + pq[2][r16];
        mean[r] = S * (1.f / Dm);
        float var = Q * (1.f / Dm) - mean[r] * mean[r];
        rstd[r] = rsqrtf(var + 1e-5f);
    }
    #pragma unroll
    for (int n = 0; n < 4; n++) {
        int col = col0 + n * 16 + lr;
        float gg = g[col], bb = bt[col];
        #pragma unroll
        for (int r = 0; r < 4; r++) {
            int row = row0 + lg * 4 + r;
            size_t o = (size_t)row * Dm + col;
            float y = (acc[n][r] - mean[r]) * rstd[r] * gg + bb;
            OUTp[o] = y;
            ob[o] = f2b(y);
            if (WQ) {
                int tp = (row >= LSEQ) ? row - LSEQ : row;
                qb[o] = f2b(y + pos[(size_t)tp * Dm + col]);
            }
        }
    }
}

// -------------------- deformable sampling (vectorized) -------------
// block = 192 thr = 4 tokens x 48 lanes (8 heads x 6 d-quads)
__global__ __launch_bounds__(192) void k_sample(const __hip_bfloat16* __restrict__ V,
        const float* __restrict__ LOC, const float* __restrict__ AW,
        __hip_bfloat16* __restrict__ ATT) {
    __shared__ float aw_s[4][64];
    __shared__ float loc_s[4][128];
    int tid = threadIdx.x;
    int tg0 = blockIdx.x * 4;
    for (int idx = tid; idx < 256; idx += 192)
        aw_s[idx >> 6][idx & 63] = AW[(size_t)tg0 * 64 + idx];
    for (int idx = tid; idx < 512; idx += 192)
        loc_s[idx >> 7][idx & 127] = LOC[(size_t)tg0 * 128 + idx];
    __syncthreads();
    int tt = tid / 48, lane = tid - tt * 48;
    int h = lane / 6, dq = lane - h * 6;
    int tg = tg0 + tt;
    int b = (tg >= LSEQ) ? 1 : 0;
    const unsigned short* vb = (const unsigned short*)V + (size_t)b * LSEQ * Dm + h * HDd + dq * 4;
    float a0 = 0.f, a1 = 0.f, a2 = 0.f, a3 = 0.f;
    #pragma unroll
    for (int lp = 0; lp < 8; lp++) {
        int l = lp >> 2;
        int Wl = l ? 48 : 96, Hl = l ? 48 : 96, st = l ? N0 : 0;
        float a  = aw_s[tt][h * 8 + lp];
        float lx = loc_s[tt][(h * 8 + lp) * 2];
        float ly = loc_s[tt][(h * 8 + lp) * 2 + 1];
        float x = lx * (float)Wl - 0.5f, y = ly * (float)Hl - 0.5f;
        float x0f = floorf(x), y0f = floorf(y);
        float wx = x - x0f, wy = y - y0f;
        int x0 = (int)x0f, y0 = (int)y0f;
        #pragma unroll
        for (int cy = 0; cy < 2; cy++) {
            int yi = y0 + cy;
            float wyv = cy ? wy : 1.f - wy;
            bool vy = (yi >= 0) && (yi < Hl);
            int yc = min(max(yi, 0), Hl - 1);
            #pragma unroll
            for (int cx = 0; cx < 2; cx++) {
                int xi = x0 + cx;
                float wv = (cx ? wx : 1.f - wx) * wyv;
                bool ok = vy && (xi >= 0) && (xi < Wl);
                int xc = min(max(xi, 0), Wl - 1);
                float cw = ok ? a * wv : 0.f;
                const unsigned short* gp = vb + (size_t)(st + yc * Wl + xc) * Dm;
                ushort4 g4 = *(const ushort4*)gp;
                a0 += cw * u2f(g4.x);
                a1 += cw * u2f(g4.y);
                a2 += cw * u2f(g4.z);
                a3 += cw * u2f(g4.w);
            }
        }
    }
    ushort4 o4;
    o4.x = f2bu(a0); o4.y = f2bu(a1); o4.z = f2bu(a2); o4.w = f2bu(a3);
    *(ushort4*)((unsigned short*)ATT + (size_t)tg * Dm + h * HDd + dq * 4) = o4;
}

// -------------------- final NHWC -> NCHW write --------------------
__global__ void k_out(const float* out, float* dst) {
    int idx = blockIdx.x * 256 + threadIdx.x;
    if (idx >= Bb * Dm * LSEQ) return;
    const int M0 = Bb * Dm * N0;
    size_t src;
    if (idx < M0) {
        int b = idx / (Dm * N0); int r = idx % (Dm * N0);
        int d = r / N0, t = r % N0;
        src = ((size_t)b * LSEQ + t) * Dm + d;
    } else {
        int i2 = idx - M0;
        int b = i2 / (Dm * N1); int r = i2 % (Dm * N1);
        int d = r / N1, t = r % N1;
        src = ((size_t)b * LSEQ + N0 + t) * Dm + d;
    }
    dst[idx] = out[src];
}

extern "C" void kernel_launch(void* const* d_in, const int* in_sizes, int n_in,
                              void* d_out, int out_size, void* d_ws, size_t ws_size,
                              hipStream_t stream) {
    (void)in_sizes; (void)n_in; (void)out_size; (void)ws_size;
    const float* feat0   = (const float*)d_in[0];
    const float* feat1   = (const float*)d_in[1];
    const float* proj_w0 = (const float*)d_in[3];
    const float* proj_b0 = (const float*)d_in[4];
    const float* gn_g0   = (const float*)d_in[5];
    const float* gn_b0   = (const float*)d_in[6];
    const float* proj_w1 = (const float*)d_in[7];
    const float* proj_b1 = (const float*)d_in[8];
    const float* gn_g1   = (const float*)d_in[9];
    const float* gn_b1   = (const float*)d_in[10];
    const float* level_embed = (const float*)d_in[11];
    const float* so_W = (const float*)d_in[12];
    const float* so_b = (const float*)d_in[13];
    const float* aw_W = (const float*)d_in[14];
    const float* aw_b = (const float*)d_in[15];
    const float* vp_W = (const float*)d_in[16];
    const float* vp_b = (const float*)d_in[17];
    const float* op_W = (const float*)d_in[18];
    const float* op_b = (const float*)d_in[19];
    const float* ln1_g = (const float*)d_in[20];
    const float* ln1_b = (const float*)d_in[21];
    const float* l1_W = (const float*)d_in[22];
    const float* l1_b = (const float*)d_in[23];
    const float* l2_W = (const float*)d_in[24];
    const float* l2_b = (const float*)d_in[25];
    const float* ln2_g = (const float*)d_in[26];
    const float* ln2_b = (const float*)d_in[27];

    float* ws   = (float*)d_ws;
    float* OUT  = ws + F_OUT;
    float* PRE  = ws + F_PRE;
    float* POS  = ws + F_POS;
    float* LOC  = ws + F_LOC;
    float* AWp  = ws + F_AW;
    __hip_bfloat16* QB  = (__hip_bfloat16*)(ws + F_QB);
    __hip_bfloat16* OB  = (__hip_bfloat16*)(ws + F_OB);
    __hip_bfloat16* AH  = (__hip_bfloat16*)(ws + F_AH);   // ATT / hidden
    __hip_bfloat16* WT16 = (__hip_bfloat16*)(ws + F_WT16);
    __hip_bfloat16* VB  = (__hip_bfloat16*)(ws + F_VB);
    float* BC   = ws + F_BC;
    float* GNS  = ws + F_GNS;
    // early-phase aliases (consumed before the layer loop)
    __hip_bfloat16* FEATB = (__hip_bfloat16*)(ws + F_LOC);
    __hip_bfloat16* CWB   = (__hip_bfloat16*)(ws + F_AW);
    float* GPART = ws + F_AH;                              // 240*32*2 floats

    k_pos<<<(LSEQ * Dm + 255) / 256, 256, 0, stream>>>(POS, level_embed);
    k_prep<<<(6 * WL_STRIDE + 255) / 256, 256, 0, stream>>>(so_W, aw_W, vp_W, op_W,
        l1_W, l2_W, so_b, aw_b, WT16, BC);
    k_prepc<<<(2 * 36864 + 255) / 256, 256, 0, stream>>>(proj_w0, proj_w1, CWB);
    k_tf<<<dim3(N0 / 32, 6, 2), dim3(32, 8), 0, stream>>>(feat0, FEATB, N0, 0);
    k_tf<<<dim3(N1 / 32, 6, 2), dim3(32, 8), 0, stream>>>(feat1, FEATB, N1, N0);
    // conv as bf16 GEMM, per (b, level)
    for (int b = 0; b < 2; b++) {
        k_gemm<6, false, false, false><<<dim3(N0 / 64, 3), 256, 0, stream>>>(
            FEATB + (size_t)b * LSEQ * Dm, CWB, proj_b0, nullptr,
            PRE + (size_t)b * LSEQ * Dm, nullptr, Dm);
        k_gemm<6, false, false, false><<<dim3(N1 / 64, 3), 256, 0, stream>>>(
            FEATB + ((size_t)b * LSEQ + N0) * Dm, CWB + 36864, proj_b1, nullptr,
            PRE + ((size_t)b * LSEQ + N0) * Dm, nullptr, Dm);
    }
    k_gnp<<<240, 192, 0, stream>>>(PRE, GPART);
    k_gnf<<<128, 64, 0, stream>>>(GPART, GNS);
    k_gnnorm<<<(Bb * LSEQ * Dm + 255) / 256, 256, 0, stream>>>(PRE, GNS,
        gn_g0, gn_b0, gn_g1, gn_b1, POS, OUT, OB, QB);

    for (int i = 0; i < 6; i++) {
        const __hip_bfloat16* WL = WT16 + (size_t)i * WL_STRIDE;
        // so|aw projection (+softmax/loc) merged with value projection
        k_soawvp<<<dim3(Mrows / 16, 2), 192, 0, stream>>>(
            QB, OB, WL + WL_SOAW, WL + WL_VP, BC + i * 192,
            vp_b + (size_t)i * Dm, LOC, AWp, VB);
        k_sample<<<Mrows / 4, 192, 0, stream>>>(VB, LOC, AWp, AH);
        // output projection + residual + LN1
        k_gemm_ln<6, false><<<Mrows / 16, 192, 0, stream>>>(
            AH, WL + WL_OP, op_b + (size_t)i * Dm, OUT,
            ln1_g + (size_t)i * Dm, ln1_b + (size_t)i * Dm, nullptr,
            OUT, OB, nullptr);
        // ffn1 (relu, bf16 out)
        k_gemm<6, true, false, true><<<dim3(Mrows / 64, 4), 256, 0, stream>>>(
            OB, WL + WL_L1, l1_b + (size_t)i * FFD, nullptr, nullptr, AH, FFD);
        // ffn2 + residual + LN2 (+Q for next layer)
        k_gemm_ln<8, true><<<Mrows / 16, 192, 0, stream>>>(
            AH, WL + WL_L2, l2_b + (size_t)i * Dm, OUT,
            ln2_g + (size_t)i * Dm, ln2_b + (size_t)i * Dm, POS,
            OUT, OB, QB);
    }
    k_out<<<(Bb * Dm * LSEQ + 255) / 256, 256, 0, stream>>>(OUT, (float*)d_out);
}

// Round 5
// 847.314 us; speedup vs baseline: 3.3675x; 1.0348x over previous
//
#include <hip/hip_runtime.h>
#include <hip/hip_bf16.h>
#include <math.h>

#define Bb 2
#define Dm 192
#define NHh 8
#define HDd 24
#define N0 9216
#define N1 2304
#define LSEQ 11520
#define FFD 256
#define Mrows (Bb*LSEQ)            // 23040

typedef __attribute__((ext_vector_type(8))) short short8;
typedef __attribute__((ext_vector_type(4))) float f32x4;

// ---------------- workspace layout (float offsets) ----------------
#define F_OUT 0                         // fp32 [23040][192]
#define F_PRE (F_OUT + 4423680)         // fp32 [23040][192]  (conv out / GN src; in-loop: V fp32)
#define F_POS (F_PRE + 4423680)         // fp32 [11520][192]
#define F_LOC (F_POS + 2211840)         // fp32 [23040][64][2]   (early: FEATB bf16)
#define F_AW  (F_LOC + 2949120)         // fp32 [23040][64]      (early: CWB bf16)
#define F_QB  (F_AW + 1474560)          // bf16 [23040][192]  (Q)
#define F_OB  (F_QB + 2211840)          // bf16 [23040][192]
#define F_AH  (F_OB + 2211840)          // bf16 [23040][256]  (ATT; early: GPART)
#define F_WT16 (F_AH + 2949120)         // bf16 weights, 6*208896 elems
#define F_BC  (F_WT16 + 626688)         // fp32 [6][192] concat so|aw bias
#define F_GNS (F_BC + 1152)             // fp32 group-norm stats (128*2)
// end ~ 24.6M floats ~= 99 MB (ws = 256 MiB)

// per-layer WT16 sub-offsets (bf16 elems)
#define WL_STRIDE 208896
#define WL_SOAW 0
#define WL_VP   36864
#define WL_OP   73728
#define WL_L1   110592
#define WL_L2   159744

__device__ inline __hip_bfloat16 f2b(float f) { return __float2bfloat16(f); }
__device__ inline unsigned short f2bu(float f) {
    __hip_bfloat16 h = __float2bfloat16(f);
    return *reinterpret_cast<unsigned short*>(&h);
}

// -------------------- pos embed --------------------
__global__ void k_pos(float* pos, const float* level_embed) {
    int idx = blockIdx.x * 256 + threadIdx.x;
    if (idx >= LSEQ * Dm) return;
    int t = idx / Dm, d = idx % Dm;
    int lvl, row, col, H, W;
    if (t < N0) { lvl = 0; H = 96; W = 96; row = t / 96; col = t % 96; }
    else        { lvl = 1; H = 48; W = 48; int tl = t - N0; row = tl / 48; col = tl % 48; }
    int k = d % 96;
    float v;
    if (d < 96) v = (row + 0.5f) / ((float)H + 1e-6f) * 6.2831853071795864f;
    else        v = (col + 0.5f) / ((float)W + 1e-6f) * 6.2831853071795864f;
    float expo = (float)(k - (k & 1)) / 96.0f;
    float tm = exp2f(expo * 13.287712379549449f);   // 10000^expo
    float p = v / tm;
    float pe = (k & 1) ? cosf(p) : sinf(p);
    pos[idx] = pe + level_embed[lvl * Dm + d];
}

// -------------------- prep: transpose + bf16-convert encoder weights ----
__global__ void k_prep(const float* soW, const float* awW, const float* vpW,
        const float* opW, const float* l1W, const float* l2W,
        const float* sob, const float* awb,
        __hip_bfloat16* WT, float* BC) {
    int idx = blockIdx.x * 256 + threadIdx.x;
    if (idx < 6 * 192) {
        int i = idx / 192, n = idx % 192;
        BC[idx] = (n < 128) ? sob[i * 128 + n] : awb[i * 64 + (n - 128)];
    }
    if (idx >= 6 * WL_STRIDE) return;
    int i = idx / WL_STRIDE; int r = idx % WL_STRIDE;
    float v;
    if (r < 36864)       { int n = r / 192, k = r % 192;
        v = (n < 128) ? soW[((size_t)i * 192 + k) * 128 + n]
                      : awW[((size_t)i * 192 + k) * 64 + (n - 128)]; }
    else if (r < 73728)  { int q = r - 36864;  int n = q / 192, k = q % 192;
        v = vpW[((size_t)i * 192 + k) * 192 + n]; }
    else if (r < 110592) { int q = r - 73728;  int n = q / 192, k = q % 192;
        v = opW[((size_t)i * 192 + k) * 192 + n]; }
    else if (r < 159744) { int q = r - 110592; int n = q / 192, k = q % 192;
        v = l1W[((size_t)i * 192 + k) * 256 + n]; }
    else                 { int q = r - 159744; int n = q / 256, k = q % 256;
        v = l2W[((size_t)i * 256 + k) * 192 + n]; }
    WT[idx] = f2b(v);
}

// conv weights: proj_w is [o][c] which is exactly Bt[N][K] — just convert
__global__ void k_prepc(const float* w0, const float* w1, __hip_bfloat16* cwb) {
    int idx = blockIdx.x * 256 + threadIdx.x;
    if (idx >= 2 * 36864) return;
    const float* w = (idx < 36864) ? w0 : w1;
    int r = idx % 36864;
    cwb[idx] = f2b(w[r]);
}

// -------------------- feature transpose [b][c][t] -> bf16 [t][c] ----------
__global__ void k_tf(const float* feat, __hip_bfloat16* out, int HW, int st) {
    __shared__ float tile[32][33];
    int t0 = blockIdx.x * 32, c0 = blockIdx.y * 32, b = blockIdx.z;
    int tx = threadIdx.x, ty = threadIdx.y;
    #pragma unroll
    for (int k = 0; k < 4; k++) {
        int c = c0 + ty + k * 8;
        tile[ty + k * 8][tx] = feat[((size_t)b * Dm + c) * HW + t0 + tx];
    }
    __syncthreads();
    #pragma unroll
    for (int k = 0; k < 4; k++) {
        int t = t0 + ty + k * 8;
        out[((size_t)b * LSEQ + st + t) * Dm + c0 + tx] = f2b(tile[tx][ty + k * 8]);
    }
}

// -------------------- GN partial sums (coalesced) --------------------
__global__ __launch_bounds__(192) void k_gnp(const float* __restrict__ pre,
        float* __restrict__ part) {
    int bid = blockIdx.x;                 // 0..239
    int b = bid / 120; int r = bid % 120;
    int l = (r >= 96) ? 1 : 0; int ch = l ? (r - 96) : r;
    int start = b * LSEQ + (l ? N0 : 0) + ch * 96;
    int d = threadIdx.x;
    float s = 0.f, sq = 0.f;
    for (int t = 0; t < 96; t++) {
        float x = pre[(size_t)(start + t) * Dm + d];
        s += x; sq += x * x;
    }
    __shared__ float ls[192], lq[192];
    ls[d] = s; lq[d] = sq;
    __syncthreads();
    if (d < 32) {
        float a = 0.f, b2 = 0.f;
        #pragma unroll
        for (int j = 0; j < 6; j++) { a += ls[d * 6 + j]; b2 += lq[d * 6 + j]; }
        part[((size_t)bid * 32 + d) * 2]     = a;
        part[((size_t)bid * 32 + d) * 2 + 1] = b2;
    }
}

__global__ void k_gnf(const float* __restrict__ part, float* __restrict__ gns) {
    int bid = blockIdx.x;                 // (b,l,g): 128
    int b = bid >> 6; int l = (bid >> 5) & 1; int g = bid & 31;
    int nch = l ? 24 : 96;
    int base = b * 120 + (l ? 96 : 0);
    int tid = threadIdx.x;
    float s = 0.f, q = 0.f;
    for (int c = tid; c < nch; c += 64) {
        s += part[((size_t)(base + c) * 32 + g) * 2];
        q += part[((size_t)(base + c) * 32 + g) * 2 + 1];
    }
    for (int m = 1; m < 64; m <<= 1) { s += __shfl_xor(s, m, 64); q += __shfl_xor(q, m, 64); }
    if (tid == 0) {
        float total = (float)((l ? N1 : N0) * 6);
        float mean = s / total;
        float var = q / total - mean * mean;
        gns[bid * 2] = mean;
        gns[bid * 2 + 1] = rsqrtf(var + 1e-5f);
    }
}

// -------------------- group norm apply: OUT f32 + O bf16 + Q bf16 ----------
__global__ void k_gnnorm(const float* srcp, const float* gns,
        const float* g0, const float* b0, const float* g1, const float* b1,
        const float* pos, float* out, __hip_bfloat16* ob, __hip_bfloat16* qb) {
    int idx = blockIdx.x * 256 + threadIdx.x;
    if (idx >= Bb * LSEQ * Dm) return;
    int d = idx % Dm;
    int t = (idx / Dm) % LSEQ;
    int l = (t < N0) ? 0 : 1;
    int g = d / 6;
    int b = idx / (Dm * LSEQ);
    int sid = ((b * 2 + l) * 32 + g) * 2;
    float mean = gns[sid], rstd = gns[sid + 1];
    float gg = l ? g1[d] : g0[d];
    float bbv = l ? b1[d] : b0[d];
    float v = (srcp[idx] - mean) * rstd * gg + bbv;
    out[idx] = v;
    ob[idx] = f2b(v);
    qb[idx] = f2b(v + pos[idx - (size_t)b * LSEQ * Dm]);
}

// -------------------- bf16 MFMA GEMM (conv path) --------------------------
template<int KSTEPS>
__global__ __launch_bounds__(256) void k_gemm(
        const __hip_bfloat16* __restrict__ A,
        const __hip_bfloat16* __restrict__ Bt,
        const float* __restrict__ bias,
        float* __restrict__ Cf, int N) {
    constexpr int K = KSTEPS * 32;
    int wid = threadIdx.x >> 6, lane = threadIdx.x & 63;
    int lg = lane >> 4, lr = lane & 15;
    int row0 = blockIdx.x * 64 + wid * 16;
    int col0 = blockIdx.y * 64;
    const short* a_base = (const short*)A + (size_t)(row0 + lr) * K + lg * 8;
    const short* b_base = (const short*)Bt + (size_t)(col0 + lr) * K + lg * 8;
    f32x4 acc[4] = {};
    #pragma unroll
    for (int kk = 0; kk < KSTEPS; kk++) {
        short8 af = *(const short8*)(a_base + kk * 32);
        #pragma unroll
        for (int n = 0; n < 4; n++) {
            short8 bfr = *(const short8*)(b_base + (size_t)n * 16 * K + kk * 32);
            acc[n] = __builtin_amdgcn_mfma_f32_16x16x32_bf16(af, bfr, acc[n], 0, 0, 0);
        }
    }
    #pragma unroll
    for (int n = 0; n < 4; n++) {
        int col = col0 + n * 16 + lr;
        float bv = bias[col];
        #pragma unroll
        for (int r = 0; r < 4; r++) {
            int row = row0 + lg * 4 + r;
            Cf[(size_t)row * N + col] = acc[n][r] + bv;
        }
    }
}

// ------------- merged soaw + value-proj dispatch --------------------------
// grid (Mrows/16, 2); 192 thr = 3 waves, wave w -> cols w*64..w*64+63
// role y==0: soaw from QB (softmax+loc epilogue); y==1: vp from OB -> VF fp32
__global__ __launch_bounds__(192) void k_soawvp(
        const __hip_bfloat16* __restrict__ QB,
        const __hip_bfloat16* __restrict__ OB,
        const __hip_bfloat16* __restrict__ BtS,
        const __hip_bfloat16* __restrict__ BtV,
        const float* __restrict__ biasS,
        const float* __restrict__ biasV,
        float* __restrict__ LOC, float* __restrict__ AW,
        float* __restrict__ VF) {
    constexpr int K = 192;
    int wid = threadIdx.x >> 6, lane = threadIdx.x & 63;
    int lg = lane >> 4, lr = lane & 15;
    int row0 = blockIdx.x * 16;
    int col0 = wid * 64;
    int role = blockIdx.y;
    const short* A  = (const short*)(role ? OB : QB);
    const short* Bt = (const short*)(role ? BtV : BtS);
    const float* bias = role ? biasV : biasS;
    const short* a_base = A + (size_t)(row0 + lr) * K + lg * 8;
    const short* b_base = Bt + (size_t)(col0 + lr) * K + lg * 8;
    f32x4 acc[4] = {};
    #pragma unroll
    for (int kk = 0; kk < 6; kk++) {
        short8 af = *(const short8*)(a_base + kk * 32);
        #pragma unroll
        for (int n = 0; n < 4; n++) {
            short8 bfr = *(const short8*)(b_base + (size_t)n * 16 * K + kk * 32);
            acc[n] = __builtin_amdgcn_mfma_f32_16x16x32_bf16(af, bfr, acc[n], 0, 0, 0);
        }
    }
    #pragma unroll
    for (int n = 0; n < 4; n++) {
        float bv = bias[col0 + n * 16 + lr];
        #pragma unroll
        for (int r = 0; r < 4; r++) acc[n][r] += bv;
    }
    if (role) {
        #pragma unroll
        for (int n = 0; n < 4; n++) {
            int col = col0 + n * 16 + lr;
            #pragma unroll
            for (int r = 0; r < 4; r++) {
                int row = row0 + lg * 4 + r;
                VF[(size_t)row * Dm + col] = acc[n][r];
            }
        }
    } else if (wid == 2) {
        // attn-weight softmax: head = 8 consecutive cols within this wave
        #pragma unroll
        for (int n = 0; n < 4; n++) {
            #pragma unroll
            for (int r = 0; r < 4; r++) {
                float v = acc[n][r];
                float m = v;
                m = fmaxf(m, __shfl_xor(m, 1)); m = fmaxf(m, __shfl_xor(m, 2));
                m = fmaxf(m, __shfl_xor(m, 4));
                float e = expf(v - m);
                float sm = e;
                sm += __shfl_xor(sm, 1); sm += __shfl_xor(sm, 2); sm += __shfl_xor(sm, 4);
                int row = row0 + lg * 4 + r;
                AW[(size_t)row * 64 + n * 16 + lr] = e / sm;
            }
        }
    } else {
        // sampling locations (cols 0..127)
        #pragma unroll
        for (int r = 0; r < 4; r++) {
            int row = row0 + lg * 4 + r;
            int t = (row >= LSEQ) ? row - LSEQ : row;
            int rr, cc, Ht, Wt;
            if (t < N0) { Ht = 96; Wt = 96; rr = t / 96; cc = t % 96; }
            else        { Ht = 48; Wt = 48; int tl = t - N0; rr = tl / 48; cc = tl % 48; }
            float refx = (cc + 0.5f) / (float)Wt;
            float refy = (rr + 0.5f) / (float)Ht;
            #pragma unroll
            for (int n = 0; n < 4; n++) {
                int col = col0 + n * 16 + lr;
                int j = col >> 1, comp = col & 1;
                float sc = (j & 4) ? 48.f : 96.f;
                LOC[(size_t)row * 128 + col] = (comp ? refy : refx) + acc[n][r] / sc;
            }
        }
    }
}

// ------------- fused GEMM + bias + residual + LayerNorm (op path) ---------
// grid (Mrows/16); 192 thr = 3 waves, wave w -> cols w*64; LDS cross-wave LN
template<int KSTEPS>
__global__ __launch_bounds__(192) void k_gemm_ln(
        const __hip_bfloat16* __restrict__ A,
        const __hip_bfloat16* __restrict__ Bt,
        const float* __restrict__ bias,
        const float* __restrict__ g, const float* __restrict__ bt,
        float* __restrict__ OUTp, __hip_bfloat16* __restrict__ ob) {
    constexpr int K = KSTEPS * 32;
    int wid = threadIdx.x >> 6, lane = threadIdx.x & 63;
    int lg = lane >> 4, lr = lane & 15;
    int row0 = blockIdx.x * 16;
    int col0 = wid * 64;
    const short* a_base = (const short*)A + (size_t)(row0 + lr) * K + lg * 8;
    const short* b_base = (const short*)Bt + (size_t)(col0 + lr) * K + lg * 8;
    f32x4 acc[4] = {};
    #pragma unroll
    for (int kk = 0; kk < KSTEPS; kk++) {
        short8 af = *(const short8*)(a_base + kk * 32);
        #pragma unroll
        for (int n = 0; n < 4; n++) {
            short8 bfr = *(const short8*)(b_base + (size_t)n * 16 * K + kk * 32);
            acc[n] = __builtin_amdgcn_mfma_f32_16x16x32_bf16(af, bfr, acc[n], 0, 0, 0);
        }
    }
    float s[4] = {0.f, 0.f, 0.f, 0.f}, q[4] = {0.f, 0.f, 0.f, 0.f};
    #pragma unroll
    for (int n = 0; n < 4; n++) {
        int col = col0 + n * 16 + lr;
        float bv = bias[col];
        #pragma unroll
        for (int r = 0; r < 4; r++) {
            size_t o = (size_t)(row0 + lg * 4 + r) * Dm + col;
            float v = acc[n][r] + bv + OUTp[o];
            acc[n][r] = v;
            s[r] += v; q[r] += v * v;
        }
    }
    #pragma unroll
    for (int r = 0; r < 4; r++) {
        #pragma unroll
        for (int m = 1; m < 16; m <<= 1) {
            s[r] += __shfl_xor(s[r], m); q[r] += __shfl_xor(q[r], m);
        }
    }
    __shared__ float ps[3][16], pq[3][16];
    if (lr == 0) {
        #pragma unroll
        for (int r = 0; r < 4; r++) {
            ps[wid][lg * 4 + r] = s[r];
            pq[wid][lg * 4 + r] = q[r];
        }
    }
    __syncthreads();
    float mean[4], rstd[4];
    #pragma unroll
    for (int r = 0; r < 4; r++) {
        int r16 = lg * 4 + r;
        float S = ps[0][r16] + ps[1][r16] + ps[2][r16];
        float Q = pq[0][r16] + pq[1][r16] + pq[2][r16];
        mean[r] = S * (1.f / Dm);
        float var = Q * (1.f / Dm) - mean[r] * mean[r];
        rstd[r] = rsqrtf(var + 1e-5f);
    }
    #pragma unroll
    for (int n = 0; n < 4; n++) {
        int col = col0 + n * 16 + lr;
        float gg = g[col], bb = bt[col];
        #pragma unroll
        for (int r = 0; r < 4; r++) {
            int row = row0 + lg * 4 + r;
            size_t o = (size_t)row * Dm + col;
            float y = (acc[n][r] - mean[r]) * rstd[r] * gg + bb;
            OUTp[o] = y;
            ob[o] = f2b(y);
        }
    }
}

// ------------- fused FFN: gemm1+relu -> LDS -> gemm2 + resid + LN2 + Q ----
// grid (Mrows/16); 256 thr = 4 waves. Phase1: wave w -> hidden cols w*64.
// Phase2: wave w -> out cols w*48. Hidden kept in LDS (row pad 8 shorts).
__global__ __launch_bounds__(256) void k_ffn(
        const __hip_bfloat16* __restrict__ A,      // OB
        const __hip_bfloat16* __restrict__ Bt1,    // [256][192]
        const float* __restrict__ b1,
        const __hip_bfloat16* __restrict__ Bt2,    // [192][256]
        const float* __restrict__ b2,
        const float* __restrict__ g, const float* __restrict__ bt,
        const float* __restrict__ pos,
        float* __restrict__ OUTp, __hip_bfloat16* __restrict__ ob,
        __hip_bfloat16* __restrict__ qb) {
    __shared__ short hid[16][264];
    __shared__ float ps[4][16], pq[4][16];
    int tid = threadIdx.x;
    int wid = tid >> 6, lane = tid & 63, lg = lane >> 4, lr = lane & 15;
    int row0 = blockIdx.x * 16;
    {   // ffn1: 16 x 64 per wave, K=192
        const short* a_base = (const short*)A + (size_t)(row0 + lr) * 192 + lg * 8;
        const short* b_base = (const short*)Bt1 + (size_t)(wid * 64 + lr) * 192 + lg * 8;
        f32x4 acc[4] = {};
        #pragma unroll
        for (int kk = 0; kk < 6; kk++) {
            short8 af = *(const short8*)(a_base + kk * 32);
            #pragma unroll
            for (int n = 0; n < 4; n++) {
                short8 bfr = *(const short8*)(b_base + (size_t)n * 16 * 192 + kk * 32);
                acc[n] = __builtin_amdgcn_mfma_f32_16x16x32_bf16(af, bfr, acc[n], 0, 0, 0);
            }
        }
        #pragma unroll
        for (int n = 0; n < 4; n++) {
            int col = wid * 64 + n * 16 + lr;
            float bv = b1[col];
            #pragma unroll
            for (int r = 0; r < 4; r++)
                hid[lg * 4 + r][col] = (short)f2bu(fmaxf(acc[n][r] + bv, 0.f));
        }
    }
    __syncthreads();
    // ffn2: 16 x 48 per wave, K=256 from LDS
    f32x4 acc2[3] = {};
    {
        const short* b_base = (const short*)Bt2 + (size_t)(wid * 48 + lr) * 256 + lg * 8;
        #pragma unroll
        for (int kk = 0; kk < 8; kk++) {
            short8 af = *(const short8*)&hid[lr][lg * 8 + kk * 32];
            #pragma unroll
            for (int n = 0; n < 3; n++) {
                short8 bfr = *(const short8*)(b_base + (size_t)n * 16 * 256 + kk * 32);
                acc2[n] = __builtin_amdgcn_mfma_f32_16x16x32_bf16(af, bfr, acc2[n], 0, 0, 0);
            }
        }
    }
    float s[4] = {0.f, 0.f, 0.f, 0.f}, q[4] = {0.f, 0.f, 0.f, 0.f};
    #pragma unroll
    for (int n = 0; n < 3; n++) {
        int col = wid * 48 + n * 16 + lr;
        float bv = b2[col];
        #pragma unroll
        for (int r = 0; r < 4; r++) {
            size_t o = (size_t)(row0 + lg * 4 + r) * Dm + col;
            float v = acc2[n][r] + bv + OUTp[o];
            acc2[n][r] = v;
            s[r] += v; q[r] += v * v;
        }
    }
    #pragma unroll
    for (int r = 0; r < 4; r++) {
        #pragma unroll
        for (int m = 1; m < 16; m <<= 1) {
            s[r] += __shfl_xor(s[r], m); q[r] += __shfl_xor(q[r], m);
        }
    }
    if (lr == 0) {
        #pragma unroll
        for (int r = 0; r < 4; r++) {
            ps[wid][lg * 4 + r] = s[r];
            pq[wid][lg * 4 + r] = q[r];
        }
    }
    __syncthreads();
    float mean[4], rstd[4];
    #pragma unroll
    for (int r = 0; r < 4; r++) {
        int r16 = lg * 4 + r;
        float S = ps[0][r16] + ps[1][r16] + ps[2][r16] + ps[3][r16];
        float Q = pq[0][r16] + pq[1][r16] + pq[2][r16] + pq[3][r16];
        mean[r] = S * (1.f / Dm);
        float var = Q * (1.f / Dm) - mean[r] * mean[r];
        rstd[r] = rsqrtf(var + 1e-5f);
    }
    #pragma unroll
    for (int n = 0; n < 3; n++) {
        int col = wid * 48 + n * 16 + lr;
        float gg = g[col], bb = bt[col];
        #pragma unroll
        for (int r = 0; r < 4; r++) {
            int row = row0 + lg * 4 + r;
            size_t o = (size_t)row * Dm + col;
            float y = (acc2[n][r] - mean[r]) * rstd[r] * gg + bb;
            OUTp[o] = y;
            ob[o] = f2b(y);
            int tp = (row >= LSEQ) ? row - LSEQ : row;
            qb[o] = f2b(y + pos[(size_t)tp * Dm + col]);
        }
    }
}

// -------------------- deformable sampling (fp32 V, vectorized) -------------
// block = 192 thr = 4 tokens x 48 lanes (8 heads x 6 d-quads)
__global__ __launch_bounds__(192) void k_sample(const float* __restrict__ V,
        const float* __restrict__ LOC, const float* __restrict__ AW,
        __hip_bfloat16* __restrict__ ATT) {
    __shared__ float aw_s[4][64];
    __shared__ float loc_s[4][128];
    int tid = threadIdx.x;
    int tg0 = blockIdx.x * 4;
    for (int idx = tid; idx < 256; idx += 192)
        aw_s[idx >> 6][idx & 63] = AW[(size_t)tg0 * 64 + idx];
    for (int idx = tid; idx < 512; idx += 192)
        loc_s[idx >> 7][idx & 127] = LOC[(size_t)tg0 * 128 + idx];
    __syncthreads();
    int tt = tid / 48, lane = tid - tt * 48;
    int h = lane / 6, dq = lane - h * 6;
    int tg = tg0 + tt;
    int b = (tg >= LSEQ) ? 1 : 0;
    const float* vb = V + (size_t)b * LSEQ * Dm + h * HDd + dq * 4;
    float a0 = 0.f, a1 = 0.f, a2 = 0.f, a3 = 0.f;
    #pragma unroll
    for (int lp = 0; lp < 8; lp++) {
        int l = lp >> 2;
        int Wl = l ? 48 : 96, Hl = l ? 48 : 96, st = l ? N0 : 0;
        float a  = aw_s[tt][h * 8 + lp];
        float lx = loc_s[tt][(h * 8 + lp) * 2];
        float ly = loc_s[tt][(h * 8 + lp) * 2 + 1];
        float x = lx * (float)Wl - 0.5f, y = ly * (float)Hl - 0.5f;
        float x0f = floorf(x), y0f = floorf(y);
        float wx = x - x0f, wy = y - y0f;
        int x0 = (int)x0f, y0 = (int)y0f;
        #pragma unroll
        for (int cy = 0; cy < 2; cy++) {
            int yi = y0 + cy;
            float wyv = cy ? wy : 1.f - wy;
            bool vy = (yi >= 0) && (yi < Hl);
            int yc = min(max(yi, 0), Hl - 1);
            #pragma unroll
            for (int cx = 0; cx < 2; cx++) {
                int xi = x0 + cx;
                float wv = (cx ? wx : 1.f - wx) * wyv;
                bool ok = vy && (xi >= 0) && (xi < Wl);
                int xc = min(max(xi, 0), Wl - 1);
                float cw = ok ? a * wv : 0.f;
                float4 g4 = *(const float4*)(vb + (size_t)(st + yc * Wl + xc) * Dm);
                a0 += cw * g4.x; a1 += cw * g4.y;
                a2 += cw * g4.z; a3 += cw * g4.w;
            }
        }
    }
    ushort4 o4;
    o4.x = f2bu(a0); o4.y = f2bu(a1); o4.z = f2bu(a2); o4.w = f2bu(a3);
    *(ushort4*)((unsigned short*)ATT + (size_t)tg * Dm + h * HDd + dq * 4) = o4;
}

// -------------------- final [t][d] -> [d][t] tiled transpose ---------------
__global__ void k_outt(const float* __restrict__ out, float* __restrict__ dst,
        int HW, int st) {
    __shared__ float tile[32][33];
    int t0 = blockIdx.x * 32, d0 = blockIdx.y * 32, b = blockIdx.z;
    int tx = threadIdx.x, ty = threadIdx.y;
    #pragma unroll
    for (int k = 0; k < 4; k++) {
        int t = t0 + ty + k * 8;
        tile[ty + k * 8][tx] = out[((size_t)b * LSEQ + st + t) * Dm + d0 + tx];
    }
    __syncthreads();
    #pragma unroll
    for (int k = 0; k < 4; k++) {
        int d = d0 + ty + k * 8;
        dst[((size_t)b * Dm + d) * HW + t0 + tx] = tile[tx][ty + k * 8];
    }
}

extern "C" void kernel_launch(void* const* d_in, const int* in_sizes, int n_in,
                              void* d_out, int out_size, void* d_ws, size_t ws_size,
                              hipStream_t stream) {
    (void)in_sizes; (void)n_in; (void)out_size; (void)ws_size;
    const float* feat0   = (const float*)d_in[0];
    const float* feat1   = (const float*)d_in[1];
    const float* proj_w0 = (const float*)d_in[3];
    const float* proj_b0 = (const float*)d_in[4];
    const float* gn_g0   = (const float*)d_in[5];
    const float* gn_b0   = (const float*)d_in[6];
    const float* proj_w1 = (const float*)d_in[7];
    const float* proj_b1 = (const float*)d_in[8];
    const float* gn_g1   = (const float*)d_in[9];
    const float* gn_b1   = (const float*)d_in[10];
    const float* level_embed = (const float*)d_in[11];
    const float* so_W = (const float*)d_in[12];
    const float* so_b = (const float*)d_in[13];
    const float* aw_W = (const float*)d_in[14];
    const float* aw_b = (const float*)d_in[15];
    const float* vp_W = (const float*)d_in[16];
    const float* vp_b = (const float*)d_in[17];
    const float* op_W = (const float*)d_in[18];
    const float* op_b = (const float*)d_in[19];
    const float* ln1_g = (const float*)d_in[20];
    const float* ln1_b = (const float*)d_in[21];
    const float* l1_W = (const float*)d_in[22];
    const float* l1_b = (const float*)d_in[23];
    const float* l2_W = (const float*)d_in[24];
    const float* l2_b = (const float*)d_in[25];
    const float* ln2_g = (const float*)d_in[26];
    const float* ln2_b = (const float*)d_in[27];

    float* ws   = (float*)d_ws;
    float* OUT  = ws + F_OUT;
    float* PRE  = ws + F_PRE;          // conv-out / GN src; in-loop: V fp32
    float* POS  = ws + F_POS;
    float* LOC  = ws + F_LOC;
    float* AWp  = ws + F_AW;
    __hip_bfloat16* QB  = (__hip_bfloat16*)(ws + F_QB);
    __hip_bfloat16* OB  = (__hip_bfloat16*)(ws + F_OB);
    __hip_bfloat16* AH  = (__hip_bfloat16*)(ws + F_AH);   // ATT
    __hip_bfloat16* WT16 = (__hip_bfloat16*)(ws + F_WT16);
    float* BC   = ws + F_BC;
    float* GNS  = ws + F_GNS;
    // early-phase aliases (consumed before the layer loop)
    __hip_bfloat16* FEATB = (__hip_bfloat16*)(ws + F_LOC);
    __hip_bfloat16* CWB   = (__hip_bfloat16*)(ws + F_AW);
    float* GPART = ws + F_AH;                              // 240*32*2 floats

    k_pos<<<(LSEQ * Dm + 255) / 256, 256, 0, stream>>>(POS, level_embed);
    k_prep<<<(6 * WL_STRIDE + 255) / 256, 256, 0, stream>>>(so_W, aw_W, vp_W, op_W,
        l1_W, l2_W, so_b, aw_b, WT16, BC);
    k_prepc<<<(2 * 36864 + 255) / 256, 256, 0, stream>>>(proj_w0, proj_w1, CWB);
    k_tf<<<dim3(N0 / 32, 6, 2), dim3(32, 8), 0, stream>>>(feat0, FEATB, N0, 0);
    k_tf<<<dim3(N1 / 32, 6, 2), dim3(32, 8), 0, stream>>>(feat1, FEATB, N1, N0);
    for (int b = 0; b < 2; b++) {
        k_gemm<6><<<dim3(N0 / 64, 3), 256, 0, stream>>>(
            FEATB + (size_t)b * LSEQ * Dm, CWB, proj_b0,
            PRE + (size_t)b * LSEQ * Dm, Dm);
        k_gemm<6><<<dim3(N1 / 64, 3), 256, 0, stream>>>(
            FEATB + ((size_t)b * LSEQ + N0) * Dm, CWB + 36864, proj_b1,
            PRE + ((size_t)b * LSEQ + N0) * Dm, Dm);
    }
    k_gnp<<<240, 192, 0, stream>>>(PRE, GPART);
    k_gnf<<<128, 64, 0, stream>>>(GPART, GNS);
    k_gnnorm<<<(Bb * LSEQ * Dm + 255) / 256, 256, 0, stream>>>(PRE, GNS,
        gn_g0, gn_b0, gn_g1, gn_b1, POS, OUT, OB, QB);

    for (int i = 0; i < 6; i++) {
        const __hip_bfloat16* WL = WT16 + (size_t)i * WL_STRIDE;
        // so|aw projection (+softmax/loc) merged with value projection (V fp32 -> PRE)
        k_soawvp<<<dim3(Mrows / 16, 2), 192, 0, stream>>>(
            QB, OB, WL + WL_SOAW, WL + WL_VP, BC + i * 192,
            vp_b + (size_t)i * Dm, LOC, AWp, PRE);
        k_sample<<<Mrows / 4, 192, 0, stream>>>(PRE, LOC, AWp, AH);
        // output projection + residual + LN1
        k_gemm_ln<6><<<Mrows / 16, 192, 0, stream>>>(
            AH, WL + WL_OP, op_b + (size_t)i * Dm,
            ln1_g + (size_t)i * Dm, ln1_b + (size_t)i * Dm, OUT, OB);
        // fused FFN + residual + LN2 + Q
        k_ffn<<<Mrows / 16, 256, 0, stream>>>(
            OB, WL + WL_L1, l1_b + (size_t)i * FFD,
            WL + WL_L2, l2_b + (size_t)i * Dm,
            ln2_g + (size_t)i * Dm, ln2_b + (size_t)i * Dm, POS,
            OUT, OB, QB);
    }
    k_outt<<<dim3(N0 / 32, 6, 2), dim3(32, 8), 0, stream>>>(OUT, (float*)d_out, N0, 0);
    k_outt<<<dim3(N1 / 32, 6, 2), dim3(32, 8), 0, stream>>>(OUT,
        (float*)d_out + (size_t)Bb * Dm * N0, N1, N0);
}

// Round 6
// 720.160 us; speedup vs baseline: 3.9621x; 1.1766x over previous
//
#include <hip/hip_runtime.h>
#include <hip/hip_bf16.h>
#include <math.h>

#define Bb 2
#define Dm 192
#define NHh 8
#define HDd 24
#define N0 9216
#define N1 2304
#define LSEQ 11520
#define FFD 256
#define Mrows (Bb*LSEQ)            // 23040

typedef __attribute__((ext_vector_type(8))) short short8;
typedef __attribute__((ext_vector_type(4))) float f32x4;

// ---------------- workspace layout (float offsets) ----------------
#define F_OUT 0                         // fp32 [23040][192]
#define F_PRE (F_OUT + 4423680)         // fp32 [23040][192]  (conv out / GN src; in-loop: V fp32)
#define F_POS (F_PRE + 4423680)         // fp32 [11520][192]
#define F_LOC (F_POS + 2211840)         // fp32 [23040][64][2]   (early: FEATB bf16)
#define F_AW  (F_LOC + 2949120)         // fp32 [23040][64]      (early: CWB bf16)
#define F_QB  (F_AW + 1474560)          // bf16 [23040][192]  (Q)
#define F_OB  (F_QB + 2211840)          // bf16 [23040][192]
#define F_AH  (F_OB + 2211840)          // bf16 [23040][256]  (ATT; early: GPART)
#define F_WT16 (F_AH + 2949120)         // bf16 weights, 6*208896 elems
#define F_BC  (F_WT16 + 626688)         // fp32 [6][192] concat so|aw bias
#define F_GNS (F_BC + 1152)             // fp32 group-norm stats (128*2)
// end ~ 24.6M floats ~= 99 MB (ws = 256 MiB)

// per-layer WT16 sub-offsets (bf16 elems)
#define WL_STRIDE 208896
#define WL_SOAW 0
#define WL_VP   36864
#define WL_OP   73728
#define WL_L1   110592
#define WL_L2   159744

__device__ inline __hip_bfloat16 f2b(float f) { return __float2bfloat16(f); }
__device__ inline unsigned short f2bu(float f) {
    __hip_bfloat16 h = __float2bfloat16(f);
    return *reinterpret_cast<unsigned short*>(&h);
}

// -------------------- pos embed --------------------
__global__ void k_pos(float* pos, const float* level_embed) {
    int idx = blockIdx.x * 256 + threadIdx.x;
    if (idx >= LSEQ * Dm) return;
    int t = idx / Dm, d = idx % Dm;
    int lvl, row, col, H, W;
    if (t < N0) { lvl = 0; H = 96; W = 96; row = t / 96; col = t % 96; }
    else        { lvl = 1; H = 48; W = 48; int tl = t - N0; row = tl / 48; col = tl % 48; }
    int k = d % 96;
    float v;
    if (d < 96) v = (row + 0.5f) / ((float)H + 1e-6f) * 6.2831853071795864f;
    else        v = (col + 0.5f) / ((float)W + 1e-6f) * 6.2831853071795864f;
    float expo = (float)(k - (k & 1)) / 96.0f;
    float tm = exp2f(expo * 13.287712379549449f);   // 10000^expo
    float p = v / tm;
    float pe = (k & 1) ? cosf(p) : sinf(p);
    pos[idx] = pe + level_embed[lvl * Dm + d];
}

// -------------------- prep: transpose + bf16-convert encoder weights ----
__global__ void k_prep(const float* soW, const float* awW, const float* vpW,
        const float* opW, const float* l1W, const float* l2W,
        const float* sob, const float* awb,
        __hip_bfloat16* WT, float* BC) {
    int idx = blockIdx.x * 256 + threadIdx.x;
    if (idx < 6 * 192) {
        int i = idx / 192, n = idx % 192;
        BC[idx] = (n < 128) ? sob[i * 128 + n] : awb[i * 64 + (n - 128)];
    }
    if (idx >= 6 * WL_STRIDE) return;
    int i = idx / WL_STRIDE; int r = idx % WL_STRIDE;
    float v;
    if (r < 36864)       { int n = r / 192, k = r % 192;
        v = (n < 128) ? soW[((size_t)i * 192 + k) * 128 + n]
                      : awW[((size_t)i * 192 + k) * 64 + (n - 128)]; }
    else if (r < 73728)  { int q = r - 36864;  int n = q / 192, k = q % 192;
        v = vpW[((size_t)i * 192 + k) * 192 + n]; }
    else if (r < 110592) { int q = r - 73728;  int n = q / 192, k = q % 192;
        v = opW[((size_t)i * 192 + k) * 192 + n]; }
    else if (r < 159744) { int q = r - 110592; int n = q / 192, k = q % 192;
        v = l1W[((size_t)i * 192 + k) * 256 + n]; }
    else                 { int q = r - 159744; int n = q / 256, k = q % 256;
        v = l2W[((size_t)i * 256 + k) * 192 + n]; }
    WT[idx] = f2b(v);
}

// conv weights: proj_w is [o][c] which is exactly Bt[N][K] — just convert
__global__ void k_prepc(const float* w0, const float* w1, __hip_bfloat16* cwb) {
    int idx = blockIdx.x * 256 + threadIdx.x;
    if (idx >= 2 * 36864) return;
    const float* w = (idx < 36864) ? w0 : w1;
    int r = idx % 36864;
    cwb[idx] = f2b(w[r]);
}

// -------------------- feature transpose [b][c][t] -> bf16 [t][c] ----------
__global__ void k_tf(const float* feat, __hip_bfloat16* out, int HW, int st) {
    __shared__ float tile[32][33];
    int t0 = blockIdx.x * 32, c0 = blockIdx.y * 32, b = blockIdx.z;
    int tx = threadIdx.x, ty = threadIdx.y;
    #pragma unroll
    for (int k = 0; k < 4; k++) {
        int c = c0 + ty + k * 8;
        tile[ty + k * 8][tx] = feat[((size_t)b * Dm + c) * HW + t0 + tx];
    }
    __syncthreads();
    #pragma unroll
    for (int k = 0; k < 4; k++) {
        int t = t0 + ty + k * 8;
        out[((size_t)b * LSEQ + st + t) * Dm + c0 + tx] = f2b(tile[tx][ty + k * 8]);
    }
}

// -------------------- GN partial sums (coalesced) --------------------
__global__ __launch_bounds__(192) void k_gnp(const float* __restrict__ pre,
        float* __restrict__ part) {
    int bid = blockIdx.x;                 // 0..239
    int b = bid / 120; int r = bid % 120;
    int l = (r >= 96) ? 1 : 0; int ch = l ? (r - 96) : r;
    int start = b * LSEQ + (l ? N0 : 0) + ch * 96;
    int d = threadIdx.x;
    float s = 0.f, sq = 0.f;
    for (int t = 0; t < 96; t++) {
        float x = pre[(size_t)(start + t) * Dm + d];
        s += x; sq += x * x;
    }
    __shared__ float ls[192], lq[192];
    ls[d] = s; lq[d] = sq;
    __syncthreads();
    if (d < 32) {
        float a = 0.f, b2 = 0.f;
        #pragma unroll
        for (int j = 0; j < 6; j++) { a += ls[d * 6 + j]; b2 += lq[d * 6 + j]; }
        part[((size_t)bid * 32 + d) * 2]     = a;
        part[((size_t)bid * 32 + d) * 2 + 1] = b2;
    }
}

__global__ void k_gnf(const float* __restrict__ part, float* __restrict__ gns) {
    int bid = blockIdx.x;                 // (b,l,g): 128
    int b = bid >> 6; int l = (bid >> 5) & 1; int g = bid & 31;
    int nch = l ? 24 : 96;
    int base = b * 120 + (l ? 96 : 0);
    int tid = threadIdx.x;
    float s = 0.f, q = 0.f;
    for (int c = tid; c < nch; c += 64) {
        s += part[((size_t)(base + c) * 32 + g) * 2];
        q += part[((size_t)(base + c) * 32 + g) * 2 + 1];
    }
    for (int m = 1; m < 64; m <<= 1) { s += __shfl_xor(s, m, 64); q += __shfl_xor(q, m, 64); }
    if (tid == 0) {
        float total = (float)((l ? N1 : N0) * 6);
        float mean = s / total;
        float var = q / total - mean * mean;
        gns[bid * 2] = mean;
        gns[bid * 2 + 1] = rsqrtf(var + 1e-5f);
    }
}

// -------------------- group norm apply: OUT f32 + O bf16 + Q bf16 ----------
__global__ void k_gnnorm(const float* srcp, const float* gns,
        const float* g0, const float* b0, const float* g1, const float* b1,
        const float* pos, float* out, __hip_bfloat16* ob, __hip_bfloat16* qb) {
    int idx = blockIdx.x * 256 + threadIdx.x;
    if (idx >= Bb * LSEQ * Dm) return;
    int d = idx % Dm;
    int t = (idx / Dm) % LSEQ;
    int l = (t < N0) ? 0 : 1;
    int g = d / 6;
    int b = idx / (Dm * LSEQ);
    int sid = ((b * 2 + l) * 32 + g) * 2;
    float mean = gns[sid], rstd = gns[sid + 1];
    float gg = l ? g1[d] : g0[d];
    float bbv = l ? b1[d] : b0[d];
    float v = (srcp[idx] - mean) * rstd * gg + bbv;
    out[idx] = v;
    ob[idx] = f2b(v);
    qb[idx] = f2b(v + pos[idx - (size_t)b * LSEQ * Dm]);
}

// -------------------- bf16 MFMA GEMM (conv path) --------------------------
template<int KSTEPS>
__global__ __launch_bounds__(256) void k_gemm(
        const __hip_bfloat16* __restrict__ A,
        const __hip_bfloat16* __restrict__ Bt,
        const float* __restrict__ bias,
        float* __restrict__ Cf, int N) {
    constexpr int K = KSTEPS * 32;
    int wid = threadIdx.x >> 6, lane = threadIdx.x & 63;
    int lg = lane >> 4, lr = lane & 15;
    int row0 = blockIdx.x * 64 + wid * 16;
    int col0 = blockIdx.y * 64;
    const short* a_base = (const short*)A + (size_t)(row0 + lr) * K + lg * 8;
    const short* b_base = (const short*)Bt + (size_t)(col0 + lr) * K + lg * 8;
    f32x4 acc[4] = {};
    #pragma unroll
    for (int kk = 0; kk < KSTEPS; kk++) {
        short8 af = *(const short8*)(a_base + kk * 32);
        #pragma unroll
        for (int n = 0; n < 4; n++) {
            short8 bfr = *(const short8*)(b_base + (size_t)n * 16 * K + kk * 32);
            acc[n] = __builtin_amdgcn_mfma_f32_16x16x32_bf16(af, bfr, acc[n], 0, 0, 0);
        }
    }
    #pragma unroll
    for (int n = 0; n < 4; n++) {
        int col = col0 + n * 16 + lr;
        float bv = bias[col];
        #pragma unroll
        for (int r = 0; r < 4; r++) {
            int row = row0 + lg * 4 + r;
            Cf[(size_t)row * N + col] = acc[n][r] + bv;
        }
    }
}

// ------------- merged soaw + value-proj dispatch (BM=32, regs-held B) -----
// grid (Mrows/32, 2); 192 thr = 3 waves, wave w -> cols w*64..w*64+63
// role y==0: soaw from QB (softmax+loc epilogue); y==1: vp from OB -> VF fp32
__global__ __launch_bounds__(192) void k_soawvp(
        const __hip_bfloat16* __restrict__ QB,
        const __hip_bfloat16* __restrict__ OB,
        const __hip_bfloat16* __restrict__ BtS,
        const __hip_bfloat16* __restrict__ BtV,
        const float* __restrict__ biasS,
        const float* __restrict__ biasV,
        float* __restrict__ LOC, float* __restrict__ AW,
        float* __restrict__ VF) {
    constexpr int K = 192;
    int wid = threadIdx.x >> 6, lane = threadIdx.x & 63;
    int lg = lane >> 4, lr = lane & 15;
    int row0 = blockIdx.x * 32;
    int col0 = wid * 64;
    int role = blockIdx.y;
    const short* A  = (const short*)(role ? OB : QB);
    const short* Bt = (const short*)(role ? BtV : BtS);
    const float* bias = role ? biasV : biasS;
    short8 bw[24];
    {
        const short* b_base = Bt + (size_t)(col0 + lr) * K + lg * 8;
        #pragma unroll
        for (int n = 0; n < 4; n++)
            #pragma unroll
            for (int kk = 0; kk < 6; kk++)
                bw[n * 6 + kk] = *(const short8*)(b_base + (size_t)n * 16 * K + kk * 32);
    }
    #pragma unroll
    for (int rg = 0; rg < 2; rg++) {
        const short* a_base = A + (size_t)(row0 + rg * 16 + lr) * K + lg * 8;
        f32x4 acc[4] = {};
        #pragma unroll
        for (int kk = 0; kk < 6; kk++) {
            short8 af = *(const short8*)(a_base + kk * 32);
            #pragma unroll
            for (int n = 0; n < 4; n++)
                acc[n] = __builtin_amdgcn_mfma_f32_16x16x32_bf16(af, bw[n * 6 + kk], acc[n], 0, 0, 0);
        }
        #pragma unroll
        for (int n = 0; n < 4; n++) {
            float bv = bias[col0 + n * 16 + lr];
            #pragma unroll
            for (int r = 0; r < 4; r++) acc[n][r] += bv;
        }
        int rbase = row0 + rg * 16;
        if (role) {
            #pragma unroll
            for (int n = 0; n < 4; n++) {
                int col = col0 + n * 16 + lr;
                #pragma unroll
                for (int r = 0; r < 4; r++)
                    VF[(size_t)(rbase + lg * 4 + r) * Dm + col] = acc[n][r];
            }
        } else if (wid == 2) {
            // attn-weight softmax: head = 8 consecutive cols within this wave
            #pragma unroll
            for (int n = 0; n < 4; n++) {
                #pragma unroll
                for (int r = 0; r < 4; r++) {
                    float v = acc[n][r];
                    float m = v;
                    m = fmaxf(m, __shfl_xor(m, 1)); m = fmaxf(m, __shfl_xor(m, 2));
                    m = fmaxf(m, __shfl_xor(m, 4));
                    float e = expf(v - m);
                    float sm = e;
                    sm += __shfl_xor(sm, 1); sm += __shfl_xor(sm, 2); sm += __shfl_xor(sm, 4);
                    AW[(size_t)(rbase + lg * 4 + r) * 64 + n * 16 + lr] = e / sm;
                }
            }
        } else {
            // sampling locations (cols 0..127)
            #pragma unroll
            for (int r = 0; r < 4; r++) {
                int row = rbase + lg * 4 + r;
                int t = (row >= LSEQ) ? row - LSEQ : row;
                int rr, cc, Ht, Wt;
                if (t < N0) { Ht = 96; Wt = 96; rr = t / 96; cc = t % 96; }
                else        { Ht = 48; Wt = 48; int tl = t - N0; rr = tl / 48; cc = tl % 48; }
                float refx = (cc + 0.5f) / (float)Wt;
                float refy = (rr + 0.5f) / (float)Ht;
                #pragma unroll
                for (int n = 0; n < 4; n++) {
                    int col = col0 + n * 16 + lr;
                    int j = col >> 1, comp = col & 1;
                    float sc = (j & 4) ? 48.f : 96.f;
                    LOC[(size_t)row * 128 + col] = (comp ? refy : refx) + acc[n][r] / sc;
                }
            }
        }
    }
}

// ------------- fused GEMM + bias + residual + LayerNorm (op path) ---------
// grid (Mrows/32); 192 thr = 3 waves, BM=32 2 row-groups, B-frags in regs
__global__ __launch_bounds__(192) void k_gemm_ln(
        const __hip_bfloat16* __restrict__ A,
        const __hip_bfloat16* __restrict__ Bt,
        const float* __restrict__ bias,
        const float* __restrict__ g, const float* __restrict__ bt,
        float* __restrict__ OUTp, __hip_bfloat16* __restrict__ ob) {
    constexpr int K = 192;
    int wid = threadIdx.x >> 6, lane = threadIdx.x & 63;
    int lg = lane >> 4, lr = lane & 15;
    int row0 = blockIdx.x * 32;
    int col0 = wid * 64;
    short8 bw[24];
    {
        const short* b_base = (const short*)Bt + (size_t)(col0 + lr) * K + lg * 8;
        #pragma unroll
        for (int n = 0; n < 4; n++)
            #pragma unroll
            for (int kk = 0; kk < 6; kk++)
                bw[n * 6 + kk] = *(const short8*)(b_base + (size_t)n * 16 * K + kk * 32);
    }
    __shared__ float ps[2][3][16], pq[2][3][16];
    #pragma unroll
    for (int rg = 0; rg < 2; rg++) {
        const short* a_base = (const short*)A + (size_t)(row0 + rg * 16 + lr) * K + lg * 8;
        f32x4 acc[4] = {};
        #pragma unroll
        for (int kk = 0; kk < 6; kk++) {
            short8 af = *(const short8*)(a_base + kk * 32);
            #pragma unroll
            for (int n = 0; n < 4; n++)
                acc[n] = __builtin_amdgcn_mfma_f32_16x16x32_bf16(af, bw[n * 6 + kk], acc[n], 0, 0, 0);
        }
        float s[4] = {0.f, 0.f, 0.f, 0.f}, q[4] = {0.f, 0.f, 0.f, 0.f};
        int rbase = row0 + rg * 16;
        #pragma unroll
        for (int n = 0; n < 4; n++) {
            int col = col0 + n * 16 + lr;
            float bv = bias[col];
            #pragma unroll
            for (int r = 0; r < 4; r++) {
                size_t o = (size_t)(rbase + lg * 4 + r) * Dm + col;
                float v = acc[n][r] + bv + OUTp[o];
                acc[n][r] = v;
                s[r] += v; q[r] += v * v;
            }
        }
        #pragma unroll
        for (int r = 0; r < 4; r++) {
            #pragma unroll
            for (int m = 1; m < 16; m <<= 1) {
                s[r] += __shfl_xor(s[r], m); q[r] += __shfl_xor(q[r], m);
            }
        }
        if (lr == 0) {
            #pragma unroll
            for (int r = 0; r < 4; r++) {
                ps[rg][wid][lg * 4 + r] = s[r];
                pq[rg][wid][lg * 4 + r] = q[r];
            }
        }
        __syncthreads();
        float mean[4], rstd[4];
        #pragma unroll
        for (int r = 0; r < 4; r++) {
            int r16 = lg * 4 + r;
            float S = ps[rg][0][r16] + ps[rg][1][r16] + ps[rg][2][r16];
            float Q = pq[rg][0][r16] + pq[rg][1][r16] + pq[rg][2][r16];
            mean[r] = S * (1.f / Dm);
            float var = Q * (1.f / Dm) - mean[r] * mean[r];
            rstd[r] = rsqrtf(var + 1e-5f);
        }
        #pragma unroll
        for (int n = 0; n < 4; n++) {
            int col = col0 + n * 16 + lr;
            float gg = g[col], bb = bt[col];
            #pragma unroll
            for (int r = 0; r < 4; r++) {
                size_t o = (size_t)(rbase + lg * 4 + r) * Dm + col;
                float y = (acc[n][r] - mean[r]) * rstd[r] * gg + bb;
                OUTp[o] = y;
                ob[o] = f2b(y);
            }
        }
    }
}

// ------------- fused FFN (BM=32, regs-held weights) -----------------------
// grid (Mrows/32); 256 thr = 4 waves. Phase1: wave w -> hidden cols w*64.
// Phase2: wave w -> out cols w*48. Hidden in LDS (row pad 8 shorts).
__global__ __launch_bounds__(256) void k_ffn(
        const __hip_bfloat16* __restrict__ A,      // OB
        const __hip_bfloat16* __restrict__ Bt1,    // [256][192]
        const float* __restrict__ b1,
        const __hip_bfloat16* __restrict__ Bt2,    // [192][256]
        const float* __restrict__ b2,
        const float* __restrict__ g, const float* __restrict__ bt,
        const float* __restrict__ pos,
        float* __restrict__ OUTp, __hip_bfloat16* __restrict__ ob,
        __hip_bfloat16* __restrict__ qb) {
    __shared__ short hid[32][264];
    __shared__ float ps[2][4][16], pq[2][4][16];
    int tid = threadIdx.x;
    int wid = tid >> 6, lane = tid & 63, lg = lane >> 4, lr = lane & 15;
    int row0 = blockIdx.x * 32;
    {   // ffn1: B-frags in regs, 2 row-groups
        short8 bw[24];
        const short* b_base = (const short*)Bt1 + (size_t)(wid * 64 + lr) * 192 + lg * 8;
        #pragma unroll
        for (int n = 0; n < 4; n++)
            #pragma unroll
            for (int kk = 0; kk < 6; kk++)
                bw[n * 6 + kk] = *(const short8*)(b_base + (size_t)n * 16 * 192 + kk * 32);
        #pragma unroll
        for (int rg = 0; rg < 2; rg++) {
            const short* a_base = (const short*)A + (size_t)(row0 + rg * 16 + lr) * 192 + lg * 8;
            f32x4 acc[4] = {};
            #pragma unroll
            for (int kk = 0; kk < 6; kk++) {
                short8 af = *(const short8*)(a_base + kk * 32);
                #pragma unroll
                for (int n = 0; n < 4; n++)
                    acc[n] = __builtin_amdgcn_mfma_f32_16x16x32_bf16(af, bw[n * 6 + kk], acc[n], 0, 0, 0);
            }
            #pragma unroll
            for (int n = 0; n < 4; n++) {
                int col = wid * 64 + n * 16 + lr;
                float bv = b1[col];
                #pragma unroll
                for (int r = 0; r < 4; r++)
                    hid[rg * 16 + lg * 4 + r][col] = (short)f2bu(fmaxf(acc[n][r] + bv, 0.f));
            }
        }
    }
    __syncthreads();
    // ffn2: 16 x 48 per wave, K=256 from LDS, B-frags in regs
    short8 bw2[24];
    {
        const short* b_base = (const short*)Bt2 + (size_t)(wid * 48 + lr) * 256 + lg * 8;
        #pragma unroll
        for (int n = 0; n < 3; n++)
            #pragma unroll
            for (int kk = 0; kk < 8; kk++)
                bw2[n * 8 + kk] = *(const short8*)(b_base + (size_t)n * 16 * 256 + kk * 32);
    }
    #pragma unroll
    for (int rg = 0; rg < 2; rg++) {
        f32x4 acc2[3] = {};
        #pragma unroll
        for (int kk = 0; kk < 8; kk++) {
            short8 af = *(const short8*)&hid[rg * 16 + lr][lg * 8 + kk * 32];
            #pragma unroll
            for (int n = 0; n < 3; n++)
                acc2[n] = __builtin_amdgcn_mfma_f32_16x16x32_bf16(af, bw2[n * 8 + kk], acc2[n], 0, 0, 0);
        }
        float s[4] = {0.f, 0.f, 0.f, 0.f}, q[4] = {0.f, 0.f, 0.f, 0.f};
        int rbase = row0 + rg * 16;
        #pragma unroll
        for (int n = 0; n < 3; n++) {
            int col = wid * 48 + n * 16 + lr;
            float bv = b2[col];
            #pragma unroll
            for (int r = 0; r < 4; r++) {
                size_t o = (size_t)(rbase + lg * 4 + r) * Dm + col;
                float v = acc2[n][r] + bv + OUTp[o];
                acc2[n][r] = v;
                s[r] += v; q[r] += v * v;
            }
        }
        #pragma unroll
        for (int r = 0; r < 4; r++) {
            #pragma unroll
            for (int m = 1; m < 16; m <<= 1) {
                s[r] += __shfl_xor(s[r], m); q[r] += __shfl_xor(q[r], m);
            }
        }
        if (lr == 0) {
            #pragma unroll
            for (int r = 0; r < 4; r++) {
                ps[rg][wid][lg * 4 + r] = s[r];
                pq[rg][wid][lg * 4 + r] = q[r];
            }
        }
        __syncthreads();
        float mean[4], rstd[4];
        #pragma unroll
        for (int r = 0; r < 4; r++) {
            int r16 = lg * 4 + r;
            float S = ps[rg][0][r16] + ps[rg][1][r16] + ps[rg][2][r16] + ps[rg][3][r16];
            float Q = pq[rg][0][r16] + pq[rg][1][r16] + pq[rg][2][r16] + pq[rg][3][r16];
            mean[r] = S * (1.f / Dm);
            float var = Q * (1.f / Dm) - mean[r] * mean[r];
            rstd[r] = rsqrtf(var + 1e-5f);
        }
        #pragma unroll
        for (int n = 0; n < 3; n++) {
            int col = wid * 48 + n * 16 + lr;
            float gg = g[col], bb = bt[col];
            #pragma unroll
            for (int r = 0; r < 4; r++) {
                int row = rbase + lg * 4 + r;
                size_t o = (size_t)row * Dm + col;
                float y = (acc2[n][r] - mean[r]) * rstd[r] * gg + bb;
                OUTp[o] = y;
                ob[o] = f2b(y);
                int tp = (row >= LSEQ) ? row - LSEQ : row;
                qb[o] = f2b(y + pos[(size_t)tp * Dm + col]);
            }
        }
    }
}

// -------------------- deformable sampling (fp32 V, vectorized) -------------
// block = 192 thr = 4 tokens x 48 lanes (8 heads x 6 d-quads)
__global__ __launch_bounds__(192) void k_sample(const float* __restrict__ V,
        const float* __restrict__ LOC, const float* __restrict__ AW,
        __hip_bfloat16* __restrict__ ATT) {
    __shared__ float aw_s[4][64];
    __shared__ float loc_s[4][128];
    int tid = threadIdx.x;
    int tg0 = blockIdx.x * 4;
    for (int idx = tid; idx < 256; idx += 192)
        aw_s[idx >> 6][idx & 63] = AW[(size_t)tg0 * 64 + idx];
    for (int idx = tid; idx < 512; idx += 192)
        loc_s[idx >> 7][idx & 127] = LOC[(size_t)tg0 * 128 + idx];
    __syncthreads();
    int tt = tid / 48, lane = tid - tt * 48;
    int h = lane / 6, dq = lane - h * 6;
    int tg = tg0 + tt;
    int b = (tg >= LSEQ) ? 1 : 0;
    const float* vb = V + (size_t)b * LSEQ * Dm + h * HDd + dq * 4;
    float a0 = 0.f, a1 = 0.f, a2 = 0.f, a3 = 0.f;
    #pragma unroll
    for (int lp = 0; lp < 8; lp++) {
        int l = lp >> 2;
        int Wl = l ? 48 : 96, Hl = l ? 48 : 96, st = l ? N0 : 0;
        float a  = aw_s[tt][h * 8 + lp];
        float lx = loc_s[tt][(h * 8 + lp) * 2];
        float ly = loc_s[tt][(h * 8 + lp) * 2 + 1];
        float x = lx * (float)Wl - 0.5f, y = ly * (float)Hl - 0.5f;
        float x0f = floorf(x), y0f = floorf(y);
        float wx = x - x0f, wy = y - y0f;
        int x0 = (int)x0f, y0 = (int)y0f;
        #pragma unroll
        for (int cy = 0; cy < 2; cy++) {
            int yi = y0 + cy;
            float wyv = cy ? wy : 1.f - wy;
            bool vy = (yi >= 0) && (yi < Hl);
            int yc = min(max(yi, 0), Hl - 1);
            #pragma unroll
            for (int cx = 0; cx < 2; cx++) {
                int xi = x0 + cx;
                float wv = (cx ? wx : 1.f - wx) * wyv;
                bool ok = vy && (xi >= 0) && (xi < Wl);
                int xc = min(max(xi, 0), Wl - 1);
                float cw = ok ? a * wv : 0.f;
                float4 g4 = *(const float4*)(vb + (size_t)(st + yc * Wl + xc) * Dm);
                a0 += cw * g4.x; a1 += cw * g4.y;
                a2 += cw * g4.z; a3 += cw * g4.w;
            }
        }
    }
    ushort4 o4;
    o4.x = f2bu(a0); o4.y = f2bu(a1); o4.z = f2bu(a2); o4.w = f2bu(a3);
    *(ushort4*)((unsigned short*)ATT + (size_t)tg * Dm + h * HDd + dq * 4) = o4;
}

// -------------------- final [t][d] -> [d][t] tiled transpose ---------------
__global__ void k_outt(const float* __restrict__ out, float* __restrict__ dst,
        int HW, int st) {
    __shared__ float tile[32][33];
    int t0 = blockIdx.x * 32, d0 = blockIdx.y * 32, b = blockIdx.z;
    int tx = threadIdx.x, ty = threadIdx.y;
    #pragma unroll
    for (int k = 0; k < 4; k++) {
        int t = t0 + ty + k * 8;
        tile[ty + k * 8][tx] = out[((size_t)b * LSEQ + st + t) * Dm + d0 + tx];
    }
    __syncthreads();
    #pragma unroll
    for (int k = 0; k < 4; k++) {
        int d = d0 + ty + k * 8;
        dst[((size_t)b * Dm + d) * HW + t0 + tx] = tile[tx][ty + k * 8];
    }
}

extern "C" void kernel_launch(void* const* d_in, const int* in_sizes, int n_in,
                              void* d_out, int out_size, void* d_ws, size_t ws_size,
                              hipStream_t stream) {
    (void)in_sizes; (void)n_in; (void)out_size; (void)ws_size;
    const float* feat0   = (const float*)d_in[0];
    const float* feat1   = (const float*)d_in[1];
    const float* proj_w0 = (const float*)d_in[3];
    const float* proj_b0 = (const float*)d_in[4];
    const float* gn_g0   = (const float*)d_in[5];
    const float* gn_b0   = (const float*)d_in[6];
    const float* proj_w1 = (const float*)d_in[7];
    const float* proj_b1 = (const float*)d_in[8];
    const float* gn_g1   = (const float*)d_in[9];
    const float* gn_b1   = (const float*)d_in[10];
    const float* level_embed = (const float*)d_in[11];
    const float* so_W = (const float*)d_in[12];
    const float* so_b = (const float*)d_in[13];
    const float* aw_W = (const float*)d_in[14];
    const float* aw_b = (const float*)d_in[15];
    const float* vp_W = (const float*)d_in[16];
    const float* vp_b = (const float*)d_in[17];
    const float* op_W = (const float*)d_in[18];
    const float* op_b = (const float*)d_in[19];
    const float* ln1_g = (const float*)d_in[20];
    const float* ln1_b = (const float*)d_in[21];
    const float* l1_W = (const float*)d_in[22];
    const float* l1_b = (const float*)d_in[23];
    const float* l2_W = (const float*)d_in[24];
    const float* l2_b = (const float*)d_in[25];
    const float* ln2_g = (const float*)d_in[26];
    const float* ln2_b = (const float*)d_in[27];

    float* ws   = (float*)d_ws;
    float* OUT  = ws + F_OUT;
    float* PRE  = ws + F_PRE;          // conv-out / GN src; in-loop: V fp32
    float* POS  = ws + F_POS;
    float* LOC  = ws + F_LOC;
    float* AWp  = ws + F_AW;
    __hip_bfloat16* QB  = (__hip_bfloat16*)(ws + F_QB);
    __hip_bfloat16* OB  = (__hip_bfloat16*)(ws + F_OB);
    __hip_bfloat16* AH  = (__hip_bfloat16*)(ws + F_AH);   // ATT
    __hip_bfloat16* WT16 = (__hip_bfloat16*)(ws + F_WT16);
    float* BC   = ws + F_BC;
    float* GNS  = ws + F_GNS;
    // early-phase aliases (consumed before the layer loop)
    __hip_bfloat16* FEATB = (__hip_bfloat16*)(ws + F_LOC);
    __hip_bfloat16* CWB   = (__hip_bfloat16*)(ws + F_AW);
    float* GPART = ws + F_AH;                              // 240*32*2 floats

    k_pos<<<(LSEQ * Dm + 255) / 256, 256, 0, stream>>>(POS, level_embed);
    k_prep<<<(6 * WL_STRIDE + 255) / 256, 256, 0, stream>>>(so_W, aw_W, vp_W, op_W,
        l1_W, l2_W, so_b, aw_b, WT16, BC);
    k_prepc<<<(2 * 36864 + 255) / 256, 256, 0, stream>>>(proj_w0, proj_w1, CWB);
    k_tf<<<dim3(N0 / 32, 6, 2), dim3(32, 8), 0, stream>>>(feat0, FEATB, N0, 0);
    k_tf<<<dim3(N1 / 32, 6, 2), dim3(32, 8), 0, stream>>>(feat1, FEATB, N1, N0);
    for (int b = 0; b < 2; b++) {
        k_gemm<6><<<dim3(N0 / 64, 3), 256, 0, stream>>>(
            FEATB + (size_t)b * LSEQ * Dm, CWB, proj_b0,
            PRE + (size_t)b * LSEQ * Dm, Dm);
        k_gemm<6><<<dim3(N1 / 64, 3), 256, 0, stream>>>(
            FEATB + ((size_t)b * LSEQ + N0) * Dm, CWB + 36864, proj_b1,
            PRE + ((size_t)b * LSEQ + N0) * Dm, Dm);
    }
    k_gnp<<<240, 192, 0, stream>>>(PRE, GPART);
    k_gnf<<<128, 64, 0, stream>>>(GPART, GNS);
    k_gnnorm<<<(Bb * LSEQ * Dm + 255) / 256, 256, 0, stream>>>(PRE, GNS,
        gn_g0, gn_b0, gn_g1, gn_b1, POS, OUT, OB, QB);

    for (int i = 0; i < 6; i++) {
        const __hip_bfloat16* WL = WT16 + (size_t)i * WL_STRIDE;
        // so|aw projection (+softmax/loc) merged with value projection (V fp32 -> PRE)
        k_soawvp<<<dim3(Mrows / 32, 2), 192, 0, stream>>>(
            QB, OB, WL + WL_SOAW, WL + WL_VP, BC + i * 192,
            vp_b + (size_t)i * Dm, LOC, AWp, PRE);
        k_sample<<<Mrows / 4, 192, 0, stream>>>(PRE, LOC, AWp, AH);
        // output projection + residual + LN1
        k_gemm_ln<<<Mrows / 32, 192, 0, stream>>>(
            AH, WL + WL_OP, op_b + (size_t)i * Dm,
            ln1_g + (size_t)i * Dm, ln1_b + (size_t)i * Dm, OUT, OB);
        // fused FFN + residual + LN2 + Q
        k_ffn<<<Mrows / 32, 256, 0, stream>>>(
            OB, WL + WL_L1, l1_b + (size_t)i * FFD,
            WL + WL_L2, l2_b + (size_t)i * Dm,
            ln2_g + (size_t)i * Dm, ln2_b + (size_t)i * Dm, POS,
            OUT, OB, QB);
    }
    k_outt<<<dim3(N0 / 32, 6, 2), dim3(32, 8), 0, stream>>>(OUT, (float*)d_out, N0, 0);
    k_outt<<<dim3(N1 / 32, 6, 2), dim3(32, 8), 0, stream>>>(OUT,
        (float*)d_out + (size_t)Bb * Dm * N0, N1, N0);
}